// Round 1
// baseline (9490.853 us; speedup 1.0000x reference)
//
#include <hip/hip_runtime.h>

#define BLK 256

__device__ __forceinline__ float4 ld4(const float* p) { return *(const float4*)p; }

// ---------------- degree / norm precompute ----------------
__global__ __launch_bounds__(BLK) void fill1_k(float* p, int n) {
    int g = blockIdx.x * BLK + threadIdx.x;
    if (g < n) p[g] = 1.0f;  // self-loop contributes 1 to degree
}
__global__ __launch_bounds__(BLK) void count_k(const int* __restrict__ cols, float* deg, int E) {
    int g = blockIdx.x * BLK + threadIdx.x;
    if (g < E) atomicAdd(&deg[cols[g]], 1.0f);
}
__global__ __launch_bounds__(BLK) void rsqrt_k(float* p, int n) {
    int g = blockIdx.x * BLK + threadIdx.x;
    if (g < n) p[g] = 1.0f / sqrtf(p[g]);  // deg >= 1 always (self-loop)
}
__global__ __launch_bounds__(BLK) void norm_k(const int* __restrict__ rows, const int* __restrict__ cols,
                                              const float* __restrict__ dinv, float* __restrict__ nrm, int E) {
    int g = blockIdx.x * BLK + threadIdx.x;
    if (g < E) nrm[g] = dinv[rows[g]] * dinv[cols[g]];
}

// ---------------- GEMM: out = f_out( f_in(H) @ W ) ----------------
// f_in  = optional (+bin, relu) applied to H elements (deferred bias+relu of prev layer)
// f_out = optional (+bout [, relu])
// One block handles ROWS=4096/FO rows and ALL FO columns; W staged in LDS in K-chunks.
template<int FI, int FO, bool INB, bool OUTB, bool OUTRELU>
__global__ __launch_bounds__(BLK) void gemm_k(const float* __restrict__ H, const float* __restrict__ Wm,
                                              const float* __restrict__ bin, const float* __restrict__ bout,
                                              float* __restrict__ out, int n)
{
    constexpr int COLT = FO / 4;        // threads across columns (float4 each)
    constexpr int RTH  = BLK / COLT;    // thread-groups across rows
    constexpr int RPT  = 4;             // rows per thread
    constexpr int ROWS = RTH * RPT;     // rows per block = 4096/FO
    constexpr int KC   = (FI > 64) ? 64 : FI;
    constexpr int NKB  = FI / KC;

    __shared__ float Wl[KC * FO];
    __shared__ float Hl[ROWS * (KC + 1)];   // +1 pad breaks bank aliasing

    const int tid    = threadIdx.x;
    const int colIdx = tid % COLT;
    const int rowIdx = tid / COLT;
    const long rowBase = (long)blockIdx.x * ROWS;

    float4 acc[RPT];
#pragma unroll
    for (int i = 0; i < RPT; i++) acc[i] = make_float4(0.f, 0.f, 0.f, 0.f);

    for (int kb = 0; kb < NKB; kb++) {
        if (kb) __syncthreads();
        // stage W chunk (KC x FO)
        for (int f = tid * 4; f < KC * FO; f += BLK * 4) {
            const int kr = f / FO, c = f % FO;
            *(float4*)&Wl[kr * FO + c] = ld4(&Wm[(kb * KC + kr) * FO + c]);
        }
        // stage H chunk (ROWS x KC), with optional deferred bias+relu
        for (int f = tid * 4; f < ROWS * KC; f += BLK * 4) {
            const int rr = f / KC, kk = f % KC;
            const long r = rowBase + rr;
            float4 v = make_float4(0.f, 0.f, 0.f, 0.f);
            if (r < n) v = ld4(&H[r * FI + kb * KC + kk]);
            if (INB) {
                float4 b4 = ld4(&bin[kb * KC + kk]);
                v.x = fmaxf(v.x + b4.x, 0.f); v.y = fmaxf(v.y + b4.y, 0.f);
                v.z = fmaxf(v.z + b4.z, 0.f); v.w = fmaxf(v.w + b4.w, 0.f);
            }
            float* dst = &Hl[rr * (KC + 1) + kk];
            dst[0] = v.x; dst[1] = v.y; dst[2] = v.z; dst[3] = v.w;
        }
        __syncthreads();
#pragma unroll 8
        for (int k = 0; k < KC; k++) {
            const float4 w4 = *(const float4*)&Wl[k * FO + 4 * colIdx];
#pragma unroll
            for (int i = 0; i < RPT; i++) {
                const float hv = Hl[(rowIdx * RPT + i) * (KC + 1) + k];
                acc[i].x = fmaf(hv, w4.x, acc[i].x);
                acc[i].y = fmaf(hv, w4.y, acc[i].y);
                acc[i].z = fmaf(hv, w4.z, acc[i].z);
                acc[i].w = fmaf(hv, w4.w, acc[i].w);
            }
        }
    }

    float4 bo = make_float4(0.f, 0.f, 0.f, 0.f);
    if (OUTB) bo = ld4(&bout[4 * colIdx]);
#pragma unroll
    for (int i = 0; i < RPT; i++) {
        const long r = rowBase + rowIdx * RPT + i;
        if (r < n) {
            float4 v = acc[i];
            if (OUTB) { v.x += bo.x; v.y += bo.y; v.z += bo.z; v.w += bo.w; }
            if (OUTRELU) {
                v.x = fmaxf(v.x, 0.f); v.y = fmaxf(v.y, 0.f);
                v.z = fmaxf(v.z, 0.f); v.w = fmaxf(v.w, 0.f);
            }
            *(float4*)&out[r * FO + 4 * colIdx] = v;
        }
    }
}

// ---------------- agg init: agg[i] = f(T[i]) * dinv[i]^2  (self-loop term + zero-init) --------
template<int WD, bool INB>
__global__ __launch_bounds__(BLK) void initagg_k(const float* __restrict__ T, const float* __restrict__ dinv,
                                                 const float* __restrict__ bin, float* __restrict__ agg, int n)
{
    constexpr int QP = WD / 4;
    const int gid = blockIdx.x * BLK + threadIdx.x;
    const int i = gid / QP;
    if (i >= n) return;
    const int q = (gid % QP) * 4;
    const float d = dinv[i];
    const float dd = d * d;
    float4 v = ld4(&T[(long)i * WD + q]);
    if (INB) {
        float4 b4 = ld4(&bin[q]);
        v.x = fmaxf(v.x + b4.x, 0.f); v.y = fmaxf(v.y + b4.y, 0.f);
        v.z = fmaxf(v.z + b4.z, 0.f); v.w = fmaxf(v.w + b4.w, 0.f);
    }
    float4 o; o.x = v.x * dd; o.y = v.y * dd; o.z = v.z * dd; o.w = v.w * dd;
    *(float4*)&agg[(long)i * WD + q] = o;
}

// ---------------- edge scatter: agg[col] += f(T[row]) * norm[e] ----------------
template<int WD, bool INB>
__global__ __launch_bounds__(BLK) void scatter_k(const float* __restrict__ T, const int* __restrict__ rows,
                                                 const int* __restrict__ cols, const float* __restrict__ nrm,
                                                 const float* __restrict__ bin, float* __restrict__ agg, int E)
{
    constexpr int QP = WD / 4;
    const int gid = blockIdx.x * BLK + threadIdx.x;
    const int e = gid / QP;
    if (e >= E) return;
    const int q = (gid % QP) * 4;
    const int r = rows[e];
    const int c = cols[e];
    const float nm = nrm[e];
    float4 v = ld4(&T[(long)r * WD + q]);
    if (INB) {
        float4 b4 = ld4(&bin[q]);
        v.x = fmaxf(v.x + b4.x, 0.f); v.y = fmaxf(v.y + b4.y, 0.f);
        v.z = fmaxf(v.z + b4.z, 0.f); v.w = fmaxf(v.w + b4.w, 0.f);
    }
    float* dst = &agg[(long)c * WD + q];
    atomicAdd(dst + 0, v.x * nm);
    atomicAdd(dst + 1, v.y * nm);
    atomicAdd(dst + 2, v.z * nm);
    atomicAdd(dst + 3, v.w * nm);
}

extern "C" void kernel_launch(void* const* d_in, const int* in_sizes, int n_in,
                              void* d_out, int out_size, void* d_ws, size_t ws_size,
                              hipStream_t stream)
{
    const float* x  = (const float*)d_in[0];
    const int*   ei = (const int*)d_in[1];
    // d_in[2] = batch (unused)
    const float* W1 = (const float*)d_in[3];  const float* b1 = (const float*)d_in[4];
    const float* W2 = (const float*)d_in[5];  const float* b2 = (const float*)d_in[6];
    const float* W3 = (const float*)d_in[7];  const float* b3 = (const float*)d_in[8];
    const float* W4 = (const float*)d_in[9];  const float* b4 = (const float*)d_in[10];
    const float* W5 = (const float*)d_in[11]; const float* b5 = (const float*)d_in[12];
    const float* W6 = (const float*)d_in[13]; const float* b6 = (const float*)d_in[14];
    const float* Wf = (const float*)d_in[15]; const float* bf = (const float*)d_in[16];

    const int n = in_sizes[0] / 128;
    const int E = in_sizes[1] / 2;
    const int* rows = ei;       // source j
    const int* cols = ei + E;   // target i

    float* dinv = (float*)d_ws;                  // n floats (deg -> dinv in place)
    float* nrm  = dinv + n;                      // E floats
    float* bufA = nrm + E;                       // n*128 floats
    float* bufB = bufA + (size_t)n * 128;        // n*128 floats
    float* out  = (float*)d_out;

    auto cdiv = [](long a, long b) { return (unsigned)((a + b - 1) / b); };

    // --- normalization precompute ---
    fill1_k<<<cdiv(n, BLK), BLK, 0, stream>>>(dinv, n);
    count_k<<<cdiv(E, BLK), BLK, 0, stream>>>(cols, dinv, E);
    rsqrt_k<<<cdiv(n, BLK), BLK, 0, stream>>>(dinv, n);
    norm_k<<<cdiv(E, BLK), BLK, 0, stream>>>(rows, cols, dinv, nrm, E);

    // L1 (128->64), linear first: t1 = x@W1; agg1 = Â t1   [deferred: +b1, relu]
    gemm_k<128, 64, false, false, false><<<cdiv(n, 64), BLK, 0, stream>>>(x, W1, nullptr, nullptr, bufA, n);
    initagg_k<64, false><<<cdiv((long)n * 16, BLK), BLK, 0, stream>>>(bufA, dinv, nullptr, bufB, n);
    scatter_k<64, false><<<cdiv((long)E * 16, BLK), BLK, 0, stream>>>(bufA, rows, cols, nrm, nullptr, bufB, E);

    // L2 (64->32), linear first: t2 = relu(agg1+b1)@W2; agg2 = Â t2   [deferred: +b2, relu]
    gemm_k<64, 32, true, false, false><<<cdiv(n, 128), BLK, 0, stream>>>(bufB, W2, b1, nullptr, bufA, n);
    initagg_k<32, false><<<cdiv((long)n * 8, BLK), BLK, 0, stream>>>(bufA, dinv, nullptr, bufB, n);
    scatter_k<32, false><<<cdiv((long)E * 8, BLK), BLK, 0, stream>>>(bufA, rows, cols, nrm, nullptr, bufB, E);

    // L3 (32->16), linear first: t3 = relu(agg2+b2)@W3; agg3 = Â t3   [deferred: +b3, relu]
    gemm_k<32, 16, true, false, false><<<cdiv(n, 256), BLK, 0, stream>>>(bufB, W3, b2, nullptr, bufA, n);
    initagg_k<16, false><<<cdiv((long)n * 4, BLK), BLK, 0, stream>>>(bufA, dinv, nullptr, bufB, n);
    scatter_k<16, false><<<cdiv((long)E * 4, BLK), BLK, 0, stream>>>(bufA, rows, cols, nrm, nullptr, bufB, E);

    // L4 (16->32), scatter first on h3=relu(agg3+b3): h4 = relu((Â h3)@W4 + b4)
    initagg_k<16, true><<<cdiv((long)n * 4, BLK), BLK, 0, stream>>>(bufB, dinv, b3, bufA, n);
    scatter_k<16, true><<<cdiv((long)E * 4, BLK), BLK, 0, stream>>>(bufB, rows, cols, nrm, b3, bufA, E);
    gemm_k<16, 32, false, true, true><<<cdiv(n, 128), BLK, 0, stream>>>(bufA, W4, nullptr, b4, bufB, n);

    // L5 (32->64), scatter first: h5 = relu((Â h4)@W5 + b5)
    initagg_k<32, false><<<cdiv((long)n * 8, BLK), BLK, 0, stream>>>(bufB, dinv, nullptr, bufA, n);
    scatter_k<32, false><<<cdiv((long)E * 8, BLK), BLK, 0, stream>>>(bufB, rows, cols, nrm, nullptr, bufA, E);
    gemm_k<32, 64, false, true, true><<<cdiv(n, 64), BLK, 0, stream>>>(bufA, W5, nullptr, b5, bufB, n);

    // L6 (64->128), scatter first: h6 = relu((Â h5)@W6 + b6)
    initagg_k<64, false><<<cdiv((long)n * 16, BLK), BLK, 0, stream>>>(bufB, dinv, nullptr, bufA, n);
    scatter_k<64, false><<<cdiv((long)E * 16, BLK), BLK, 0, stream>>>(bufB, rows, cols, nrm, nullptr, bufA, E);
    gemm_k<64, 128, false, true, true><<<cdiv(n, 32), BLK, 0, stream>>>(bufA, W6, nullptr, b6, bufB, n);

    // final: out = h6 @ Wf + bf
    gemm_k<128, 128, false, true, false><<<cdiv(n, 32), BLK, 0, stream>>>(bufB, Wf, nullptr, bf, out, n);
}

// Round 2
// 1142.491 us; speedup vs baseline: 8.3072x; 8.3072x over previous
//
#include <hip/hip_runtime.h>

#define BLK 256
#define SBS 256   // scan block size (n <= SBS*512 supported; n=100000 -> 391 blocks)

__device__ __forceinline__ float4 ld4(const float* p) { return *(const float4*)p; }

// ================= CSR build =================
__global__ __launch_bounds__(BLK) void zeroi_k(int* p, int n) {
    int g = blockIdx.x * BLK + threadIdx.x;
    if (g < n) p[g] = 0;
}
__global__ __launch_bounds__(BLK) void degcount_k(const int* __restrict__ cols, int* deg, int E) {
    int g = blockIdx.x * BLK + threadIdx.x;
    if (g < E) atomicAdd(&deg[cols[g]], 1);
}
// per-block reduce of deg -> bsum[block]
__global__ __launch_bounds__(SBS) void blockred_k(const int* __restrict__ deg, int* bsum, int n) {
    __shared__ int s[SBS];
    int g = blockIdx.x * SBS + threadIdx.x;
    s[threadIdx.x] = (g < n) ? deg[g] : 0;
    __syncthreads();
    for (int o = SBS / 2; o > 0; o >>= 1) {
        if (threadIdx.x < o) s[threadIdx.x] += s[threadIdx.x + o];
        __syncthreads();
    }
    if (threadIdx.x == 0) bsum[blockIdx.x] = s[0];
}
// single-block exclusive scan of block sums (nb <= 512)
__global__ __launch_bounds__(512) void scanbsum_k(int* bsum, int nb) {
    __shared__ int s[512];
    const int t = threadIdx.x;
    const int orig = (t < nb) ? bsum[t] : 0;
    s[t] = orig;
    __syncthreads();
    for (int o = 1; o < 512; o <<= 1) {
        int v = s[t] + ((t >= o) ? s[t - o] : 0);
        __syncthreads();
        s[t] = v;
        __syncthreads();
    }
    if (t < nb) bsum[t] = s[t] - orig;   // exclusive block offset
}
// per-block exclusive scan + block offset -> P[g] (start index). P may alias deg.
// Also emits dinv[g] = rsqrt(deg+1)  (+1 = self-loop).
__global__ __launch_bounds__(SBS) void blockscan_k(const int* __restrict__ deg, const int* __restrict__ bofs,
                                                   int* P, float* dinv, int n) {
    __shared__ int s[SBS];
    const int g = blockIdx.x * SBS + threadIdx.x;
    const int t = threadIdx.x;
    const int orig = (g < n) ? deg[g] : 0;
    s[t] = orig;
    __syncthreads();
    for (int o = 1; o < SBS; o <<= 1) {
        int v = s[t] + ((t >= o) ? s[t - o] : 0);
        __syncthreads();
        s[t] = v;
        __syncthreads();
    }
    if (g < n) {
        P[g] = bofs[blockIdx.x] + s[t] - orig;           // exclusive start
        dinv[g] = rsqrtf((float)orig + 1.0f);
    }
}
// fill: srow sorted by destination. Afterwards P[i] == start of node i+1 (end of node i).
__global__ __launch_bounds__(BLK) void fill_k(const int* __restrict__ rows, const int* __restrict__ cols,
                                              int* P, int* __restrict__ srow, int E) {
    int g = blockIdx.x * BLK + threadIdx.x;
    if (g < E) {
        int pos = atomicAdd(&P[cols[g]], 1);
        srow[pos] = rows[g];
    }
}

// ================= aggregation by gather =================
// agg[i] = dinv[i] * ( Tp[i] + sum_{e in in(i)} Tp[srow[e]] )
// where Tp rows are already pre-scaled by dinv (producer epilogue or prescale_k).
template<int WD>
__global__ __launch_bounds__(BLK) void gather_k(const float* __restrict__ Tp, const int* __restrict__ P,
                                                const int* __restrict__ srow, const float* __restrict__ dinv,
                                                float* __restrict__ agg, int n) {
    const long gid = (long)blockIdx.x * BLK + threadIdx.x;
    const int i = (int)(gid / WD);
    const int f = (int)(gid % WD);
    if (i >= n) return;
    const int start = (i == 0) ? 0 : P[i - 1];
    const int end = P[i];
    float a0 = Tp[(long)i * WD + f];   // self-loop term
    float a1 = 0.f, a2 = 0.f, a3 = 0.f;
    int e = start;
    for (; e + 4 <= end; e += 4) {
        const int j0 = srow[e], j1 = srow[e + 1], j2 = srow[e + 2], j3 = srow[e + 3];
        a0 += Tp[(long)j0 * WD + f];
        a1 += Tp[(long)j1 * WD + f];
        a2 += Tp[(long)j2 * WD + f];
        a3 += Tp[(long)j3 * WD + f];
    }
    for (; e < end; e++) a0 += Tp[(long)srow[e] * WD + f];
    agg[(long)i * WD + f] = dinv[i] * ((a0 + a1) + (a2 + a3));
}

// prescale: Tp[i] = f_in(T[i]) * dinv[i]   (f_in = optional +bias, relu)
template<int WD, bool INB>
__global__ __launch_bounds__(BLK) void prescale_k(const float* __restrict__ T, const float* __restrict__ dinv,
                                                  const float* __restrict__ bin, float* __restrict__ Tp, int n) {
    constexpr int QP = WD / 4;
    const long gid = (long)blockIdx.x * BLK + threadIdx.x;
    const int i = (int)(gid / QP);
    if (i >= n) return;
    const int q = (int)(gid % QP) * 4;
    float4 v = ld4(&T[(long)i * WD + q]);
    if (INB) {
        float4 b4 = ld4(&bin[q]);
        v.x = fmaxf(v.x + b4.x, 0.f); v.y = fmaxf(v.y + b4.y, 0.f);
        v.z = fmaxf(v.z + b4.z, 0.f); v.w = fmaxf(v.w + b4.w, 0.f);
    }
    const float d = dinv[i];
    v.x *= d; v.y *= d; v.z *= d; v.w *= d;
    *(float4*)&Tp[(long)i * WD + q] = v;
}

// ================= GEMM: out = f_out( f_in(H) @ W ) [ * dinv[row] ] =================
template<int FI, int FO, bool INB, bool OUTB, bool OUTRELU, bool OSC>
__global__ __launch_bounds__(BLK) void gemm_k(const float* __restrict__ H, const float* __restrict__ Wm,
                                              const float* __restrict__ bin, const float* __restrict__ bout,
                                              const float* __restrict__ dinv, float* __restrict__ out, int n) {
    constexpr int COLT = FO / 4;        // threads across columns (float4 each)
    constexpr int RTH  = BLK / COLT;    // thread-groups across rows
    constexpr int RPT  = 4;             // rows per thread
    constexpr int ROWS = RTH * RPT;     // rows per block
    constexpr int KC   = (FI > 64) ? 64 : FI;
    constexpr int NKB  = FI / KC;

    __shared__ float Wl[KC * FO];
    __shared__ float Hl[ROWS * (KC + 1)];

    const int tid    = threadIdx.x;
    const int colIdx = tid % COLT;
    const int rowIdx = tid / COLT;
    const long rowBase = (long)blockIdx.x * ROWS;

    float4 acc[RPT];
#pragma unroll
    for (int i = 0; i < RPT; i++) acc[i] = make_float4(0.f, 0.f, 0.f, 0.f);

    for (int kb = 0; kb < NKB; kb++) {
        if (kb) __syncthreads();
        for (int f = tid * 4; f < KC * FO; f += BLK * 4) {
            const int kr = f / FO, c = f % FO;
            *(float4*)&Wl[kr * FO + c] = ld4(&Wm[(kb * KC + kr) * FO + c]);
        }
        for (int f = tid * 4; f < ROWS * KC; f += BLK * 4) {
            const int rr = f / KC, kk = f % KC;
            const long r = rowBase + rr;
            float4 v = make_float4(0.f, 0.f, 0.f, 0.f);
            if (r < n) v = ld4(&H[r * FI + kb * KC + kk]);
            if (INB) {
                float4 b4 = ld4(&bin[kb * KC + kk]);
                v.x = fmaxf(v.x + b4.x, 0.f); v.y = fmaxf(v.y + b4.y, 0.f);
                v.z = fmaxf(v.z + b4.z, 0.f); v.w = fmaxf(v.w + b4.w, 0.f);
            }
            float* dst = &Hl[rr * (KC + 1) + kk];
            dst[0] = v.x; dst[1] = v.y; dst[2] = v.z; dst[3] = v.w;
        }
        __syncthreads();
#pragma unroll 8
        for (int k = 0; k < KC; k++) {
            const float4 w4 = *(const float4*)&Wl[k * FO + 4 * colIdx];
#pragma unroll
            for (int i = 0; i < RPT; i++) {
                const float hv = Hl[(rowIdx * RPT + i) * (KC + 1) + k];
                acc[i].x = fmaf(hv, w4.x, acc[i].x);
                acc[i].y = fmaf(hv, w4.y, acc[i].y);
                acc[i].z = fmaf(hv, w4.z, acc[i].z);
                acc[i].w = fmaf(hv, w4.w, acc[i].w);
            }
        }
    }

    float4 bo = make_float4(0.f, 0.f, 0.f, 0.f);
    if (OUTB) bo = ld4(&bout[4 * colIdx]);
#pragma unroll
    for (int i = 0; i < RPT; i++) {
        const long r = rowBase + rowIdx * RPT + i;
        if (r < n) {
            float4 v = acc[i];
            if (OUTB) { v.x += bo.x; v.y += bo.y; v.z += bo.z; v.w += bo.w; }
            if (OUTRELU) {
                v.x = fmaxf(v.x, 0.f); v.y = fmaxf(v.y, 0.f);
                v.z = fmaxf(v.z, 0.f); v.w = fmaxf(v.w, 0.f);
            }
            if (OSC) {
                const float d = dinv[r];
                v.x *= d; v.y *= d; v.z *= d; v.w *= d;
            }
            *(float4*)&out[r * FO + 4 * colIdx] = v;
        }
    }
}

extern "C" void kernel_launch(void* const* d_in, const int* in_sizes, int n_in,
                              void* d_out, int out_size, void* d_ws, size_t ws_size,
                              hipStream_t stream)
{
    const float* x  = (const float*)d_in[0];
    const int*   ei = (const int*)d_in[1];
    const float* W1 = (const float*)d_in[3];  const float* b1 = (const float*)d_in[4];
    const float* W2 = (const float*)d_in[5];  const float* b2 = (const float*)d_in[6];
    const float* W3 = (const float*)d_in[7];  const float* b3 = (const float*)d_in[8];
    const float* W4 = (const float*)d_in[9];  const float* b4 = (const float*)d_in[10];
    const float* W5 = (const float*)d_in[11]; const float* b5 = (const float*)d_in[12];
    const float* W6 = (const float*)d_in[13]; const float* b6 = (const float*)d_in[14];
    const float* Wf = (const float*)d_in[15]; const float* bf = (const float*)d_in[16];

    const int n = in_sizes[0] / 128;
    const int E = in_sizes[1] / 2;
    const int* rows = ei;       // source j
    const int* cols = ei + E;   // target i

    // workspace layout
    int*   P    = (int*)d_ws;                       // n ints (deg -> scanned starts -> ends)
    int*   bsum = P + n;                            // 512 ints
    int*   srow = bsum + 512;                       // E ints
    float* dinv = (float*)(srow + E);               // n floats
    float* bufA = dinv + n;                         // n*128 floats
    float* bufB = bufA + (size_t)n * 128;           // n*64 floats

    auto cdiv = [](long a, long b) { return (unsigned)((a + b - 1) / b); };
    const unsigned nb = cdiv(n, SBS);

    // --- CSR build (deg -> exclusive scan -> fill) ---
    zeroi_k<<<cdiv(n, BLK), BLK, 0, stream>>>(P, n);
    degcount_k<<<cdiv(E, BLK), BLK, 0, stream>>>(cols, P, E);
    blockred_k<<<nb, SBS, 0, stream>>>(P, bsum, n);
    scanbsum_k<<<1, 512, 0, stream>>>(bsum, nb);
    blockscan_k<<<nb, SBS, 0, stream>>>(P, bsum, P, dinv, n);   // in-place scan + dinv
    fill_k<<<cdiv(E, BLK), BLK, 0, stream>>>(rows, cols, P, srow, E);

    // --- layers ---
    // L1: t1' = (x@W1)*dinv ; a1 = gather(t1')          [deferred: +b1, relu]
    gemm_k<128, 64, false, false, false, true><<<cdiv(n, 64), BLK, 0, stream>>>(x, W1, nullptr, nullptr, dinv, bufA, n);
    gather_k<64><<<cdiv((long)n * 64, BLK), BLK, 0, stream>>>(bufA, P, srow, dinv, bufB, n);

    // L2: t2' = (relu(a1+b1)@W2)*dinv ; a2 = gather     [deferred: +b2, relu]
    gemm_k<64, 32, true, false, false, true><<<cdiv(n, 128), BLK, 0, stream>>>(bufB, W2, b1, nullptr, dinv, bufA, n);
    gather_k<32><<<cdiv((long)n * 32, BLK), BLK, 0, stream>>>(bufA, P, srow, dinv, bufB, n);

    // L3: t3' = (relu(a2+b2)@W3)*dinv ; a3 = gather     [deferred: +b3, relu]
    gemm_k<32, 16, true, false, false, true><<<cdiv(n, 256), BLK, 0, stream>>>(bufB, W3, b2, nullptr, dinv, bufA, n);
    gather_k<16><<<cdiv((long)n * 16, BLK), BLK, 0, stream>>>(bufA, P, srow, dinv, bufB, n);

    // L4: t4' = relu(a3+b3)*dinv ; a4 = gather ; h4' = relu(a4@W4+b4)*dinv
    prescale_k<16, true><<<cdiv((long)n * 4, BLK), BLK, 0, stream>>>(bufB, dinv, b3, bufA, n);
    gather_k<16><<<cdiv((long)n * 16, BLK), BLK, 0, stream>>>(bufA, P, srow, dinv, bufB, n);
    gemm_k<16, 32, false, true, true, true><<<cdiv(n, 128), BLK, 0, stream>>>(bufB, W4, nullptr, b4, dinv, bufA, n);

    // L5: a5 = gather(h4') ; h5' = relu(a5@W5+b5)*dinv
    gather_k<32><<<cdiv((long)n * 32, BLK), BLK, 0, stream>>>(bufA, P, srow, dinv, bufB, n);
    gemm_k<32, 64, false, true, true, true><<<cdiv(n, 64), BLK, 0, stream>>>(bufB, W5, nullptr, b5, dinv, bufA, n);

    // L6: a6 = gather(h5') ; h6 = relu(a6@W6+b6)
    gather_k<64><<<cdiv((long)n * 64, BLK), BLK, 0, stream>>>(bufA, P, srow, dinv, bufB, n);
    gemm_k<64, 128, false, true, true, false><<<cdiv(n, 32), BLK, 0, stream>>>(bufB, W6, nullptr, b6, nullptr, bufA, n);

    // final: out = h6 @ Wf + bf
    gemm_k<128, 128, false, true, false, false><<<cdiv(n, 32), BLK, 0, stream>>>(bufA, Wf, nullptr, bf, nullptr, (float*)d_out, n);
}

// Round 3
// 1083.190 us; speedup vs baseline: 8.7619x; 1.0547x over previous
//
#include <hip/hip_runtime.h>

#define BLK 256
#define SBS 256       // scan block size
#define NBSHIFT 9     // 512 nodes per bucket
#define MAXNB 200     // supports n <= 102400
#define STAGE_CAP 32  // staged pairs per bucket (LDS)
#define CAPB 20480    // slots per bucket in global pair buffer (mean 16384, sigma ~128)

__device__ __forceinline__ float4 ld4(const float* p) { return *(const float4*)p; }

// ================= CSR build =================
__global__ __launch_bounds__(BLK) void zeroi_k(int* p, int n) {
    int g = blockIdx.x * BLK + threadIdx.x;
    if (g < n) p[g] = 0;
}
__global__ __launch_bounds__(BLK) void btinit_k(int* btail, int nb) {
    int g = blockIdx.x * BLK + threadIdx.x;
    if (g < nb) btail[g] = g * CAPB;
}
__global__ __launch_bounds__(BLK) void degcount_k(const int* __restrict__ cols, int* deg, int E) {
    int g = blockIdx.x * BLK + threadIdx.x;
    if (g < E) atomicAdd(&deg[cols[g]], 1);
}
__global__ __launch_bounds__(SBS) void blockred_k(const int* __restrict__ deg, int* bsum, int n) {
    __shared__ int s[SBS];
    int g = blockIdx.x * SBS + threadIdx.x;
    s[threadIdx.x] = (g < n) ? deg[g] : 0;
    __syncthreads();
    for (int o = SBS / 2; o > 0; o >>= 1) {
        if (threadIdx.x < o) s[threadIdx.x] += s[threadIdx.x + o];
        __syncthreads();
    }
    if (threadIdx.x == 0) bsum[blockIdx.x] = s[0];
}
__global__ __launch_bounds__(512) void scanbsum_k(int* bsum, int nb) {
    __shared__ int s[512];
    const int t = threadIdx.x;
    const int orig = (t < nb) ? bsum[t] : 0;
    s[t] = orig;
    __syncthreads();
    for (int o = 1; o < 512; o <<= 1) {
        int v = s[t] + ((t >= o) ? s[t - o] : 0);
        __syncthreads();
        s[t] = v;
        __syncthreads();
    }
    if (t < nb) bsum[t] = s[t] - orig;
}
// P[g] = exclusive start (P stays as STARTS after build); dinv[g] = rsqrt(deg+1)
__global__ __launch_bounds__(SBS) void blockscan_k(const int* __restrict__ deg, const int* __restrict__ bofs,
                                                   int* P, float* dinv, int n) {
    __shared__ int s[SBS];
    const int g = blockIdx.x * SBS + threadIdx.x;
    const int t = threadIdx.x;
    const int orig = (g < n) ? deg[g] : 0;
    s[t] = orig;
    __syncthreads();
    for (int o = 1; o < SBS; o <<= 1) {
        int v = s[t] + ((t >= o) ? s[t - o] : 0);
        __syncthreads();
        s[t] = v;
        __syncthreads();
    }
    if (g < n) {
        P[g] = bofs[blockIdx.x] + s[t] - orig;
        dinv[g] = rsqrtf((float)orig + 1.0f);
    }
}

// Pass A: bin (row,col) pairs by col>>NBSHIFT into global bucket regions,
// staged through LDS, flushed in aligned 128B chunks (one writer per line).
__global__ __launch_bounds__(BLK) void bucketA_k(const int* __restrict__ rows, const int* __restrict__ cols,
                                                 int* btail, int2* __restrict__ pairs, int E, int nb) {
    __shared__ __align__(16) int2 stage[MAXNB * STAGE_CAP];
    __shared__ int cnt[MAXNB];
    const int tid = threadIdx.x;
    for (int b = tid; b < nb; b += BLK) cnt[b] = 0;
    __syncthreads();

    const int chunk = (E + gridDim.x - 1) / gridDim.x;
    const int start = blockIdx.x * chunk;
    const int end = min(E, start + chunk);

    for (int base = start; base < end; base += BLK) {
        const int e = base + tid;
        if (e < end) {
            const int r = rows[e], c = cols[e];
            const int b = c >> NBSHIFT;
            const int s = atomicAdd(&cnt[b], 1);
            if (s < STAGE_CAP) {
                stage[b * STAGE_CAP + s] = make_int2(r, c);
            } else {  // overflow (astronomically rare w/ random edges): direct spill
                const int g = atomicAdd(&btail[b], 1);
                pairs[g] = make_int2(r, c);
            }
        }
        __syncthreads();
        for (int b = tid; b < nb; b += BLK) {
            const int c0 = cnt[b];
            const int st = min(c0, STAGE_CAP);
            if (st >= 16) {
                const int g = atomicAdd(&btail[b], 16);
                if ((g & 1) == 0) {
                    const int4* src = (const int4*)&stage[b * STAGE_CAP];
#pragma unroll
                    for (int k = 0; k < 8; k++) ((int4*)&pairs[g])[k] = src[k];
                } else {
                    for (int k = 0; k < 16; k++) pairs[g + k] = stage[b * STAGE_CAP + k];
                }
                for (int k = 16; k < st; k++) stage[b * STAGE_CAP + (k - 16)] = stage[b * STAGE_CAP + k];
                cnt[b] = st - 16;
            } else if (c0 != st) {
                cnt[b] = st;
            }
        }
        __syncthreads();
    }
    // final flush, sentinel-padded to 16-pair chunks
    for (int b = tid; b < nb; b += BLK) {
        const int st = min(cnt[b], STAGE_CAP);
        if (st > 0) {
            const int padded = (st + 15) & ~15;
            for (int k = st; k < padded; k++) stage[b * STAGE_CAP + k] = make_int2(0, -1);
            const int g = atomicAdd(&btail[b], padded);
            if ((g & 1) == 0) {
                const int4* src = (const int4*)&stage[b * STAGE_CAP];
                for (int k = 0; k < padded / 2; k++) ((int4*)&pairs[g])[k] = src[k];
            } else {
                for (int k = 0; k < padded; k++) pairs[g + k] = stage[b * STAGE_CAP + k];
            }
        }
    }
}

// Pass B: one block per bucket; place rows into srow via LDS per-node tails.
// Writes land in the bucket's contiguous ~64KB srow region (block-local).
__global__ __launch_bounds__(BLK) void bucketB_k(const int2* __restrict__ pairs, const int* __restrict__ btail,
                                                 const int* __restrict__ P, int* __restrict__ srow, int n) {
    __shared__ int tail[1 << NBSHIFT];
    const int b = blockIdx.x;
    const int base = b << NBSHIFT;
    const int nnod = min(1 << NBSHIFT, n - base);
    for (int i = threadIdx.x; i < nnod; i += BLK) tail[i] = P[base + i];
    __syncthreads();
    const int hi = btail[b];
    for (int s = b * CAPB + threadIdx.x; s < hi; s += BLK) {
        const int2 pr = pairs[s];
        if (pr.y < 0) continue;
        const int pos = atomicAdd(&tail[pr.y - base], 1);
        srow[pos] = pr.x;
    }
}

// ================= aggregation by gather =================
// out[i] = g( dinv[i] * ( Tp[i] + sum_{e in in(i)} Tp[srow[e]] ) )
// PRE: g(v) = relu(v + b) * dinv[i]   (fused input transform for the next gather)
template<int WD, bool PRE>
__global__ __launch_bounds__(BLK) void gather_k(const float* __restrict__ Tp, const int* __restrict__ P,
                                                const int* __restrict__ srow, const float* __restrict__ dinv,
                                                const float* __restrict__ bin, float* __restrict__ out,
                                                int n, int E) {
    const long gid = (long)blockIdx.x * BLK + threadIdx.x;
    const int i = (int)(gid / WD);
    const int f = (int)(gid % WD);
    if (i >= n) return;
    const int start = P[i];
    const int end = (i + 1 < n) ? P[i + 1] : E;
    float a0 = Tp[(long)i * WD + f];   // self-loop
    float a1 = 0.f, a2 = 0.f, a3 = 0.f, a4 = 0.f, a5 = 0.f, a6 = 0.f, a7 = 0.f;
    int e = start;
    for (; e + 8 <= end; e += 8) {
        const int j0 = srow[e],     j1 = srow[e + 1], j2 = srow[e + 2], j3 = srow[e + 3];
        const int j4 = srow[e + 4], j5 = srow[e + 5], j6 = srow[e + 6], j7 = srow[e + 7];
        a0 += Tp[(long)j0 * WD + f]; a1 += Tp[(long)j1 * WD + f];
        a2 += Tp[(long)j2 * WD + f]; a3 += Tp[(long)j3 * WD + f];
        a4 += Tp[(long)j4 * WD + f]; a5 += Tp[(long)j5 * WD + f];
        a6 += Tp[(long)j6 * WD + f]; a7 += Tp[(long)j7 * WD + f];
    }
    for (; e < end; e++) a0 += Tp[(long)srow[e] * WD + f];
    const float d = dinv[i];
    float v = d * (((a0 + a1) + (a2 + a3)) + ((a4 + a5) + (a6 + a7)));
    if (PRE) v = fmaxf(v + bin[f], 0.f) * d;
    out[(long)i * WD + f] = v;
}

// ================= GEMM: out = f_out( f_in(H) @ W ) [ * dinv[row] ] =================
template<int FI, int FO, bool INB, bool OUTB, bool OUTRELU, bool OSC>
__global__ __launch_bounds__(BLK) void gemm_k(const float* __restrict__ H, const float* __restrict__ Wm,
                                              const float* __restrict__ bin, const float* __restrict__ bout,
                                              const float* __restrict__ dinv, float* __restrict__ out, int n) {
    constexpr int COLT = FO / 4;
    constexpr int RTH  = BLK / COLT;
    constexpr int RPT  = 4;
    constexpr int ROWS = RTH * RPT;
    constexpr int KC   = (FI > 64) ? 64 : FI;
    constexpr int NKB  = FI / KC;

    __shared__ float Wl[KC * FO];
    __shared__ float Hl[ROWS * (KC + 1)];

    const int tid    = threadIdx.x;
    const int colIdx = tid % COLT;
    const int rowIdx = tid / COLT;
    const long rowBase = (long)blockIdx.x * ROWS;

    float4 acc[RPT];
#pragma unroll
    for (int i = 0; i < RPT; i++) acc[i] = make_float4(0.f, 0.f, 0.f, 0.f);

    for (int kb = 0; kb < NKB; kb++) {
        if (kb) __syncthreads();
        for (int f = tid * 4; f < KC * FO; f += BLK * 4) {
            const int kr = f / FO, c = f % FO;
            *(float4*)&Wl[kr * FO + c] = ld4(&Wm[(kb * KC + kr) * FO + c]);
        }
        for (int f = tid * 4; f < ROWS * KC; f += BLK * 4) {
            const int rr = f / KC, kk = f % KC;
            const long r = rowBase + rr;
            float4 v = make_float4(0.f, 0.f, 0.f, 0.f);
            if (r < n) v = ld4(&H[r * FI + kb * KC + kk]);
            if (INB) {
                float4 b4 = ld4(&bin[kb * KC + kk]);
                v.x = fmaxf(v.x + b4.x, 0.f); v.y = fmaxf(v.y + b4.y, 0.f);
                v.z = fmaxf(v.z + b4.z, 0.f); v.w = fmaxf(v.w + b4.w, 0.f);
            }
            float* dst = &Hl[rr * (KC + 1) + kk];
            dst[0] = v.x; dst[1] = v.y; dst[2] = v.z; dst[3] = v.w;
        }
        __syncthreads();
#pragma unroll 8
        for (int k = 0; k < KC; k++) {
            const float4 w4 = *(const float4*)&Wl[k * FO + 4 * colIdx];
#pragma unroll
            for (int i = 0; i < RPT; i++) {
                const float hv = Hl[(rowIdx * RPT + i) * (KC + 1) + k];
                acc[i].x = fmaf(hv, w4.x, acc[i].x);
                acc[i].y = fmaf(hv, w4.y, acc[i].y);
                acc[i].z = fmaf(hv, w4.z, acc[i].z);
                acc[i].w = fmaf(hv, w4.w, acc[i].w);
            }
        }
    }

    float4 bo = make_float4(0.f, 0.f, 0.f, 0.f);
    if (OUTB) bo = ld4(&bout[4 * colIdx]);
#pragma unroll
    for (int i = 0; i < RPT; i++) {
        const long r = rowBase + rowIdx * RPT + i;
        if (r < n) {
            float4 v = acc[i];
            if (OUTB) { v.x += bo.x; v.y += bo.y; v.z += bo.z; v.w += bo.w; }
            if (OUTRELU) {
                v.x = fmaxf(v.x, 0.f); v.y = fmaxf(v.y, 0.f);
                v.z = fmaxf(v.z, 0.f); v.w = fmaxf(v.w, 0.f);
            }
            if (OSC) {
                const float d = dinv[r];
                v.x *= d; v.y *= d; v.z *= d; v.w *= d;
            }
            *(float4*)&out[r * FO + 4 * colIdx] = v;
        }
    }
}

extern "C" void kernel_launch(void* const* d_in, const int* in_sizes, int n_in,
                              void* d_out, int out_size, void* d_ws, size_t ws_size,
                              hipStream_t stream)
{
    const float* x  = (const float*)d_in[0];
    const int*   ei = (const int*)d_in[1];
    const float* W1 = (const float*)d_in[3];  const float* b1 = (const float*)d_in[4];
    const float* W2 = (const float*)d_in[5];  const float* b2 = (const float*)d_in[6];
    const float* W3 = (const float*)d_in[7];  const float* b3 = (const float*)d_in[8];
    const float* W4 = (const float*)d_in[9];  const float* b4 = (const float*)d_in[10];
    const float* W5 = (const float*)d_in[11]; const float* b5 = (const float*)d_in[12];
    const float* W6 = (const float*)d_in[13]; const float* b6 = (const float*)d_in[14];
    const float* Wf = (const float*)d_in[15]; const float* bf = (const float*)d_in[16];

    const int n = in_sizes[0] / 128;
    const int E = in_sizes[1] / 2;
    const int* rows = ei;       // source j
    const int* cols = ei + E;   // target i

    // workspace layout (all offsets 16B-aligned)
    int*   P    = (int*)d_ws;                        // n ints
    int*   bsum = P + n;                             // 512 ints
    int*   btail= bsum + 512;                        // 256 ints (nb <= 200)
    int*   srow = btail + 256;                       // E ints
    float* dinv = (float*)(srow + E);                // n floats
    float* bufA = dinv + n;                          // n*128 floats
    float* bufB = bufA + (size_t)n * 128;            // n*64 floats
    int2*  pairs= (int2*)bufA;                       // alias: nb*CAPB int2 (used only pre-layers)

    auto cdiv = [](long a, long b) { return (unsigned)((a + b - 1) / b); };
    const unsigned nsb = cdiv(n, SBS);
    const int nb = (n + (1 << NBSHIFT) - 1) >> NBSHIFT;

    // --- CSR build ---
    zeroi_k<<<cdiv(n, BLK), BLK, 0, stream>>>(P, n);
    btinit_k<<<1, BLK, 0, stream>>>(btail, nb);
    degcount_k<<<cdiv(E, BLK), BLK, 0, stream>>>(cols, P, E);
    blockred_k<<<nsb, SBS, 0, stream>>>(P, bsum, n);
    scanbsum_k<<<1, 512, 0, stream>>>(bsum, nsb);
    blockscan_k<<<nsb, SBS, 0, stream>>>(P, bsum, P, dinv, n);
    bucketA_k<<<128, BLK, 0, stream>>>(rows, cols, btail, pairs, E, nb);
    bucketB_k<<<nb, BLK, 0, stream>>>(pairs, btail, P, srow, n);

    // --- layers ---
    // L1: t1' = (x@W1)*dinv ; a1 = gather(t1')          [deferred: +b1, relu]
    gemm_k<128, 64, false, false, false, true><<<cdiv(n, 64), BLK, 0, stream>>>(x, W1, nullptr, nullptr, dinv, bufA, n);
    gather_k<64, false><<<cdiv((long)n * 64, BLK), BLK, 0, stream>>>(bufA, P, srow, dinv, nullptr, bufB, n, E);

    // L2: t2' = (relu(a1+b1)@W2)*dinv ; a2 = gather     [deferred: +b2, relu]
    gemm_k<64, 32, true, false, false, true><<<cdiv(n, 128), BLK, 0, stream>>>(bufB, W2, b1, nullptr, dinv, bufA, n);
    gather_k<32, false><<<cdiv((long)n * 32, BLK), BLK, 0, stream>>>(bufA, P, srow, dinv, nullptr, bufB, n, E);

    // L3: t3' = (relu(a2+b2)@W3)*dinv ; gather w/ fused epilogue -> t4' = relu(a3+b3)*dinv
    gemm_k<32, 16, true, false, false, true><<<cdiv(n, 256), BLK, 0, stream>>>(bufB, W3, b2, nullptr, dinv, bufA, n);
    gather_k<16, true><<<cdiv((long)n * 16, BLK), BLK, 0, stream>>>(bufA, P, srow, dinv, b3, bufB, n, E);

    // L4: a4 = gather(t4') ; h4' = relu(a4@W4+b4)*dinv
    gather_k<16, false><<<cdiv((long)n * 16, BLK), BLK, 0, stream>>>(bufB, P, srow, dinv, nullptr, bufA, n, E);
    gemm_k<16, 32, false, true, true, true><<<cdiv(n, 128), BLK, 0, stream>>>(bufA, W4, nullptr, b4, dinv, bufB, n);

    // L5: a5 = gather(h4') ; h5' = relu(a5@W5+b5)*dinv
    gather_k<32, false><<<cdiv((long)n * 32, BLK), BLK, 0, stream>>>(bufB, P, srow, dinv, nullptr, bufA, n, E);
    gemm_k<32, 64, false, true, true, true><<<cdiv(n, 64), BLK, 0, stream>>>(bufA, W5, nullptr, b5, dinv, bufB, n);

    // L6: a6 = gather(h5') ; h6 = relu(a6@W6+b6)
    gather_k<64, false><<<cdiv((long)n * 64, BLK), BLK, 0, stream>>>(bufB, P, srow, dinv, nullptr, bufA, n, E);
    gemm_k<64, 128, false, true, true, false><<<cdiv(n, 32), BLK, 0, stream>>>(bufA, W6, nullptr, b6, nullptr, bufB, n);

    // final: out = h6 @ Wf + bf
    gemm_k<128, 128, false, true, false, false><<<cdiv(n, 32), BLK, 0, stream>>>(bufB, Wf, nullptr, bf, nullptr, (float*)d_out, n);
}

// Round 5
// 1064.961 us; speedup vs baseline: 8.9119x; 1.0171x over previous
//
#include <hip/hip_runtime.h>

#define BLK 256
#define SBS 256       // scan block size
#define NBSHIFT 9     // 512 nodes per bucket
#define MAXNB 200     // supports n <= 102400
#define STAGE_CAP 32  // staged pairs per bucket (LDS)
#define CAPB 24576    // slots per bucket (mean 16327 + 512-block padding ~3840 + margin)

__device__ __forceinline__ float4 ld4(const float* p) { return *(const float4*)p; }

// ================= CSR build =================
__global__ __launch_bounds__(BLK) void zeroi_k(int* p, int n) {
    int g = blockIdx.x * BLK + threadIdx.x;
    if (g < n) p[g] = 0;
}
__global__ __launch_bounds__(BLK) void btinit_k(int* btail, int nb) {
    int g = blockIdx.x * BLK + threadIdx.x;
    if (g < nb) btail[g] = g * CAPB;
}
__global__ __launch_bounds__(BLK) void degcount_k(const int* __restrict__ cols, int* deg, int E) {
    int g = blockIdx.x * BLK + threadIdx.x;
    if (g < E) atomicAdd(&deg[cols[g]], 1);
}
__global__ __launch_bounds__(SBS) void blockred_k(const int* __restrict__ deg, int* bsum, int n) {
    __shared__ int s[SBS];
    int g = blockIdx.x * SBS + threadIdx.x;
    s[threadIdx.x] = (g < n) ? deg[g] : 0;
    __syncthreads();
    for (int o = SBS / 2; o > 0; o >>= 1) {
        if (threadIdx.x < o) s[threadIdx.x] += s[threadIdx.x + o];
        __syncthreads();
    }
    if (threadIdx.x == 0) bsum[blockIdx.x] = s[0];
}
__global__ __launch_bounds__(512) void scanbsum_k(int* bsum, int nb) {
    __shared__ int s[512];
    const int t = threadIdx.x;
    const int orig = (t < nb) ? bsum[t] : 0;
    s[t] = orig;
    __syncthreads();
    for (int o = 1; o < 512; o <<= 1) {
        int v = s[t] + ((t >= o) ? s[t - o] : 0);
        __syncthreads();
        s[t] = v;
        __syncthreads();
    }
    if (t < nb) bsum[t] = s[t] - orig;
}
// P[g] = exclusive start (P stays as STARTS after build); dinv[g] = rsqrt(deg+1)
__global__ __launch_bounds__(SBS) void blockscan_k(const int* __restrict__ deg, const int* __restrict__ bofs,
                                                   int* P, float* dinv, int n) {
    __shared__ int s[SBS];
    const int g = blockIdx.x * SBS + threadIdx.x;
    const int t = threadIdx.x;
    const int orig = (g < n) ? deg[g] : 0;
    s[t] = orig;
    __syncthreads();
    for (int o = 1; o < SBS; o <<= 1) {
        int v = s[t] + ((t >= o) ? s[t - o] : 0);
        __syncthreads();
        s[t] = v;
        __syncthreads();
    }
    if (g < n) {
        P[g] = bofs[blockIdx.x] + s[t] - orig;
        dinv[g] = rsqrtf((float)orig + 1.0f);
    }
}

// Pass A: bin (row,col) pairs by col>>NBSHIFT into global bucket regions,
// staged through LDS, flushed in aligned 128B chunks (one writer per line).
__global__ __launch_bounds__(BLK) void bucketA_k(const int* __restrict__ rows, const int* __restrict__ cols,
                                                 int* btail, int2* __restrict__ pairs, int E, int nb) {
    __shared__ __align__(16) int2 stage[MAXNB * STAGE_CAP];
    __shared__ int cnt[MAXNB];
    const int tid = threadIdx.x;
    for (int b = tid; b < nb; b += BLK) cnt[b] = 0;
    __syncthreads();

    const int chunk = (E + gridDim.x - 1) / gridDim.x;
    const int start = blockIdx.x * chunk;
    const int end = min(E, start + chunk);

    for (int base = start; base < end; base += BLK) {
        const int e = base + tid;
        if (e < end) {
            const int r = rows[e], c = cols[e];
            const int b = c >> NBSHIFT;
            const int s = atomicAdd(&cnt[b], 1);
            if (s < STAGE_CAP) {
                stage[b * STAGE_CAP + s] = make_int2(r, c);
            } else {  // overflow (astronomically rare w/ random edges): direct spill
                const int g = atomicAdd(&btail[b], 1);
                pairs[g] = make_int2(r, c);
            }
        }
        __syncthreads();
        for (int b = tid; b < nb; b += BLK) {
            const int c0 = cnt[b];
            const int st = min(c0, STAGE_CAP);
            if (st >= 16) {
                const int g = atomicAdd(&btail[b], 16);
                if ((g & 1) == 0) {
                    const int4* src = (const int4*)&stage[b * STAGE_CAP];
#pragma unroll
                    for (int k = 0; k < 8; k++) ((int4*)&pairs[g])[k] = src[k];
                } else {
                    for (int k = 0; k < 16; k++) pairs[g + k] = stage[b * STAGE_CAP + k];
                }
                for (int k = 16; k < st; k++) stage[b * STAGE_CAP + (k - 16)] = stage[b * STAGE_CAP + k];
                cnt[b] = st - 16;
            } else if (c0 != st) {
                cnt[b] = st;
            }
        }
        __syncthreads();
    }
    // final flush, sentinel-padded to 16-pair chunks
    for (int b = tid; b < nb; b += BLK) {
        const int st = min(cnt[b], STAGE_CAP);
        if (st > 0) {
            const int padded = (st + 15) & ~15;
            for (int k = st; k < padded; k++) stage[b * STAGE_CAP + k] = make_int2(0, -1);
            const int g = atomicAdd(&btail[b], padded);
            if ((g & 1) == 0) {
                const int4* src = (const int4*)&stage[b * STAGE_CAP];
                for (int k = 0; k < padded / 2; k++) ((int4*)&pairs[g])[k] = src[k];
            } else {
                for (int k = 0; k < padded; k++) pairs[g + k] = stage[b * STAGE_CAP + k];
            }
        }
    }
}

// Pass B: one block per bucket; place rows into srow via LDS per-node tails.
// Writes land in the bucket's contiguous ~64KB srow region (block-local).
__global__ __launch_bounds__(BLK) void bucketB_k(const int2* __restrict__ pairs, const int* __restrict__ btail,
                                                 const int* __restrict__ P, int* __restrict__ srow, int n) {
    __shared__ int tail[1 << NBSHIFT];
    const int b = blockIdx.x;
    const int base = b << NBSHIFT;
    const int nnod = min(1 << NBSHIFT, n - base);
    for (int i = threadIdx.x; i < nnod; i += BLK) tail[i] = P[base + i];
    __syncthreads();
    const int hi = btail[b];
    for (int s = b * CAPB + threadIdx.x; s < hi; s += BLK) {
        const int2 pr = pairs[s];
        if (pr.y < 0) continue;
        const int pos = atomicAdd(&tail[pr.y - base], 1);
        srow[pos] = pr.x;
    }
}

// ================= aggregation by gather =================
// out[i] = g( dinv[i] * ( Tp[i] + sum_{e in in(i)} Tp[srow[e]] ) )
// PRE: g(v) = relu(v + b) * dinv[i]
template<int WD, bool PRE>
__global__ __launch_bounds__(BLK) void gather_k(const float* __restrict__ Tp, const int* __restrict__ P,
                                                const int* __restrict__ srow, const float* __restrict__ dinv,
                                                const float* __restrict__ bin, float* __restrict__ out,
                                                int n, int E) {
    const long gid = (long)blockIdx.x * BLK + threadIdx.x;
    const int i = (int)(gid / WD);
    const int f = (int)(gid % WD);
    if (i >= n) return;
    const int start = P[i];
    const int end = (i + 1 < n) ? P[i + 1] : E;
    float a0 = Tp[(long)i * WD + f];   // self-loop
    float a1 = 0.f, a2 = 0.f, a3 = 0.f, a4 = 0.f, a5 = 0.f, a6 = 0.f, a7 = 0.f;
    int e = start;
    for (; e + 8 <= end; e += 8) {
        const int j0 = srow[e],     j1 = srow[e + 1], j2 = srow[e + 2], j3 = srow[e + 3];
        const int j4 = srow[e + 4], j5 = srow[e + 5], j6 = srow[e + 6], j7 = srow[e + 7];
        a0 += Tp[(long)j0 * WD + f]; a1 += Tp[(long)j1 * WD + f];
        a2 += Tp[(long)j2 * WD + f]; a3 += Tp[(long)j3 * WD + f];
        a4 += Tp[(long)j4 * WD + f]; a5 += Tp[(long)j5 * WD + f];
        a6 += Tp[(long)j6 * WD + f]; a7 += Tp[(long)j7 * WD + f];
    }
    for (; e < end; e++) a0 += Tp[(long)srow[e] * WD + f];
    const float d = dinv[i];
    float v = d * (((a0 + a1) + (a2 + a3)) + ((a4 + a5) + (a6 + a7)));
    if (PRE) v = fmaxf(v + bin[f], 0.f) * d;
    out[(long)i * WD + f] = v;
}

// ================= GEMM: out = f_out( f_in(H) @ W ) [ * dinv[row] ] =================
// RPT=8 for FO>=64: 32 FMA per k-step vs 9 LDS reads -> FMA-bound; halves W-stage traffic.
template<int FI, int FO, bool INB, bool OUTB, bool OUTRELU, bool OSC>
__global__ __launch_bounds__(BLK) void gemm_k(const float* __restrict__ H, const float* __restrict__ Wm,
                                              const float* __restrict__ bin, const float* __restrict__ bout,
                                              const float* __restrict__ dinv, float* __restrict__ out, int n) {
    constexpr int COLT = FO / 4;
    constexpr int RTH  = BLK / COLT;
    constexpr int RPT  = (FO >= 64) ? 8 : 4;
    constexpr int ROWS = RTH * RPT;
    constexpr int KC   = (FI > 64) ? 64 : FI;
    constexpr int NKB  = FI / KC;

    __shared__ float Wl[KC * FO];
    __shared__ float Hl[ROWS * (KC + 1)];

    const int tid    = threadIdx.x;
    const int colIdx = tid % COLT;
    const int rowIdx = tid / COLT;
    const long rowBase = (long)blockIdx.x * ROWS;

    float4 acc[RPT];
#pragma unroll
    for (int i = 0; i < RPT; i++) acc[i] = make_float4(0.f, 0.f, 0.f, 0.f);

    for (int kb = 0; kb < NKB; kb++) {
        if (kb) __syncthreads();
        for (int f = tid * 4; f < KC * FO; f += BLK * 4) {
            const int kr = f / FO, c = f % FO;
            *(float4*)&Wl[kr * FO + c] = ld4(&Wm[(kb * KC + kr) * FO + c]);
        }
        for (int f = tid * 4; f < ROWS * KC; f += BLK * 4) {
            const int rr = f / KC, kk = f % KC;
            const long r = rowBase + rr;
            float4 v = make_float4(0.f, 0.f, 0.f, 0.f);
            if (r < n) v = ld4(&H[r * FI + kb * KC + kk]);
            if (INB) {
                float4 b4 = ld4(&bin[kb * KC + kk]);
                v.x = fmaxf(v.x + b4.x, 0.f); v.y = fmaxf(v.y + b4.y, 0.f);
                v.z = fmaxf(v.z + b4.z, 0.f); v.w = fmaxf(v.w + b4.w, 0.f);
            }
            float* dst = &Hl[rr * (KC + 1) + kk];
            dst[0] = v.x; dst[1] = v.y; dst[2] = v.z; dst[3] = v.w;
        }
        __syncthreads();
#pragma unroll 8
        for (int k = 0; k < KC; k++) {
            const float4 w4 = *(const float4*)&Wl[k * FO + 4 * colIdx];
#pragma unroll
            for (int i = 0; i < RPT; i++) {
                const float hv = Hl[(rowIdx * RPT + i) * (KC + 1) + k];
                acc[i].x = fmaf(hv, w4.x, acc[i].x);
                acc[i].y = fmaf(hv, w4.y, acc[i].y);
                acc[i].z = fmaf(hv, w4.z, acc[i].z);
                acc[i].w = fmaf(hv, w4.w, acc[i].w);
            }
        }
    }

    float4 bo = make_float4(0.f, 0.f, 0.f, 0.f);
    if (OUTB) bo = ld4(&bout[4 * colIdx]);
#pragma unroll
    for (int i = 0; i < RPT; i++) {
        const long r = rowBase + rowIdx * RPT + i;
        if (r < n) {
            float4 v = acc[i];
            if (OUTB) { v.x += bo.x; v.y += bo.y; v.z += bo.z; v.w += bo.w; }
            if (OUTRELU) {
                v.x = fmaxf(v.x, 0.f); v.y = fmaxf(v.y, 0.f);
                v.z = fmaxf(v.z, 0.f); v.w = fmaxf(v.w, 0.f);
            }
            if (OSC) {
                const float d = dinv[r];
                v.x *= d; v.y *= d; v.z *= d; v.w *= d;
            }
            *(float4*)&out[r * FO + 4 * colIdx] = v;
        }
    }
}

extern "C" void kernel_launch(void* const* d_in, const int* in_sizes, int n_in,
                              void* d_out, int out_size, void* d_ws, size_t ws_size,
                              hipStream_t stream)
{
    const float* x  = (const float*)d_in[0];
    const int*   ei = (const int*)d_in[1];
    const float* W1 = (const float*)d_in[3];  const float* b1 = (const float*)d_in[4];
    const float* W2 = (const float*)d_in[5];  const float* b2 = (const float*)d_in[6];
    const float* W3 = (const float*)d_in[7];  const float* b3 = (const float*)d_in[8];
    const float* W4 = (const float*)d_in[9];  const float* b4 = (const float*)d_in[10];
    const float* W5 = (const float*)d_in[11]; const float* b5 = (const float*)d_in[12];
    const float* W6 = (const float*)d_in[13]; const float* b6 = (const float*)d_in[14];
    const float* Wf = (const float*)d_in[15]; const float* bf = (const float*)d_in[16];

    const int n = in_sizes[0] / 128;
    const int E = in_sizes[1] / 2;
    const int* rows = ei;       // source j
    const int* cols = ei + E;   // target i

    // workspace layout (all offsets 16B-aligned)
    int*   P    = (int*)d_ws;                        // n ints
    int*   bsum = P + n;                             // 512 ints
    int*   btail= bsum + 512;                        // 256 ints (nb <= 200)
    int*   srow = btail + 256;                       // E ints
    float* dinv = (float*)(srow + E);                // n floats
    float* bufA = dinv + n;                          // n*128 floats
    float* bufB = bufA + (size_t)n * 128;            // n*64 floats
    int2*  pairs= (int2*)bufA;                       // alias: nb*CAPB int2 (used only pre-layers; 38.5MB < 51.2MB)

    auto cdiv = [](long a, long b) { return (unsigned)((a + b - 1) / b); };
    const unsigned nsb = cdiv(n, SBS);
    const int nb = (n + (1 << NBSHIFT) - 1) >> NBSHIFT;

    // --- CSR build ---
    zeroi_k<<<cdiv(n, BLK), BLK, 0, stream>>>(P, n);
    btinit_k<<<1, BLK, 0, stream>>>(btail, nb);
    degcount_k<<<cdiv(E, BLK), BLK, 0, stream>>>(cols, P, E);
    blockred_k<<<nsb, SBS, 0, stream>>>(P, bsum, n);
    scanbsum_k<<<1, 512, 0, stream>>>(bsum, nsb);
    blockscan_k<<<nsb, SBS, 0, stream>>>(P, bsum, P, dinv, n);
    bucketA_k<<<512, BLK, 0, stream>>>(rows, cols, btail, pairs, E, nb);
    bucketB_k<<<nb, BLK, 0, stream>>>(pairs, btail, P, srow, n);

    // --- layers ---
    // L1: t1' = (x@W1)*dinv ; a1 = gather(t1')          [deferred: +b1, relu]
    gemm_k<128, 64, false, false, false, true><<<cdiv(n, 128), BLK, 0, stream>>>(x, W1, nullptr, nullptr, dinv, bufA, n);
    gather_k<64, false><<<cdiv((long)n * 64, BLK), BLK, 0, stream>>>(bufA, P, srow, dinv, nullptr, bufB, n, E);

    // L2: t2' = (relu(a1+b1)@W2)*dinv ; a2 = gather     [deferred: +b2, relu]
    gemm_k<64, 32, true, false, false, true><<<cdiv(n, 128), BLK, 0, stream>>>(bufB, W2, b1, nullptr, dinv, bufA, n);
    gather_k<32, false><<<cdiv((long)n * 32, BLK), BLK, 0, stream>>>(bufA, P, srow, dinv, nullptr, bufB, n, E);

    // L3: t3' = (relu(a2+b2)@W3)*dinv ; gather w/ fused epilogue -> t4' = relu(a3+b3)*dinv
    gemm_k<32, 16, true, false, false, true><<<cdiv(n, 256), BLK, 0, stream>>>(bufB, W3, b2, nullptr, dinv, bufA, n);
    gather_k<16, true><<<cdiv((long)n * 16, BLK), BLK, 0, stream>>>(bufA, P, srow, dinv, b3, bufB, n, E);

    // L4: a4 = gather(t4') ; h4' = relu(a4@W4+b4)*dinv
    gather_k<16, false><<<cdiv((long)n * 16, BLK), BLK, 0, stream>>>(bufB, P, srow, dinv, nullptr, bufA, n, E);
    gemm_k<16, 32, false, true, true, true><<<cdiv(n, 128), BLK, 0, stream>>>(bufA, W4, nullptr, b4, dinv, bufB, n);

    // L5: a5 = gather(h4') ; h5' = relu(a5@W5+b5)*dinv
    gather_k<32, false><<<cdiv((long)n * 32, BLK), BLK, 0, stream>>>(bufB, P, srow, dinv, nullptr, bufA, n, E);
    gemm_k<32, 64, false, true, true, true><<<cdiv(n, 128), BLK, 0, stream>>>(bufA, W5, nullptr, b5, dinv, bufB, n);

    // L6: a6 = gather(h5') ; h6 = relu(a6@W6+b6)
    gather_k<64, false><<<cdiv((long)n * 64, BLK), BLK, 0, stream>>>(bufB, P, srow, dinv, nullptr, bufA, n, E);
    gemm_k<64, 128, false, true, true, false><<<cdiv(n, 64), BLK, 0, stream>>>(bufA, W6, nullptr, b6, nullptr, bufB, n);

    // final: out = h6 @ Wf + bf
    gemm_k<128, 128, false, true, false, false><<<cdiv(n, 64), BLK, 0, stream>>>(bufB, Wf, nullptr, bf, nullptr, (float*)d_out, n);
}

// Round 6
// 847.650 us; speedup vs baseline: 11.1967x; 1.2564x over previous
//
#include <hip/hip_runtime.h>

#define BLK 256
#define NBSHIFT 9     // 512 nodes per bucket
#define MAXNB 200     // supports n <= 102400
#define GPART 512     // partition blocks

__device__ __forceinline__ float4 ld4(const float* p) { return *(const float4*)p; }

// ================= CSR build: atomic-free radix partition by col>>NBSHIFT =================
// P1: per-block histogram over buckets. hist[b*GPART + g] = count of bucket b in block g's chunk.
__global__ __launch_bounds__(BLK) void p1_hist_k(const int* __restrict__ cols, int* __restrict__ hist,
                                                 int E, int nb) {
    __shared__ int h[MAXNB];
    const int tid = threadIdx.x, g = blockIdx.x;
    for (int b = tid; b < nb; b += BLK) h[b] = 0;
    __syncthreads();
    const int chunk = (E + GPART - 1) / GPART;
    const int start = g * chunk, end = min(E, start + chunk);
    for (int e = start + tid; e < end; e += BLK) atomicAdd(&h[cols[e] >> NBSHIFT], 1);
    __syncthreads();
    for (int b = tid; b < nb; b += BLK) hist[b * GPART + g] = h[b];
}
// P2a: bucket totals + exclusive scan -> bstart[0..nb], bstart[nb]=E. Single block.
__global__ __launch_bounds__(256) void p2a_k(const int* __restrict__ hist, int* __restrict__ bstart,
                                             int nb, int E) {
    __shared__ int s[256];
    const int t = threadIdx.x;
    int tot = 0;
    if (t < nb) {
        const int* hp = &hist[t * GPART];
        for (int g = 0; g < GPART; g++) tot += hp[g];
    }
    s[t] = tot;
    __syncthreads();
    for (int o = 1; o < 256; o <<= 1) {
        int v = s[t] + ((t >= o) ? s[t - o] : 0);
        __syncthreads();
        s[t] = v;
        __syncthreads();
    }
    if (t < nb) bstart[t] = s[t] - tot;
    if (t == 0) bstart[nb] = E;
}
// P2b: per-bucket exclusive scan over its GPART block-counts, +bstart -> absolute offsets (in place).
__global__ __launch_bounds__(256) void p2b_k(int* __restrict__ hist, const int* __restrict__ bstart) {
    __shared__ int s[GPART];
    const int b = blockIdx.x, t = threadIdx.x;
    const int v0 = hist[b * GPART + t], v1 = hist[b * GPART + 256 + t];
    s[t] = v0; s[256 + t] = v1;
    __syncthreads();
    for (int o = 1; o < GPART; o <<= 1) {
        const int a0 = s[t] + ((t >= o) ? s[t - o] : 0);
        const int a1 = s[256 + t] + ((256 + t >= o) ? s[256 + t - o] : 0);
        __syncthreads();
        s[t] = a0; s[256 + t] = a1;
        __syncthreads();
    }
    const int base = bstart[b];
    hist[b * GPART + t] = base + s[t] - v0;
    hist[b * GPART + 256 + t] = base + s[256 + t] - v1;
}
// P3: partition edges into pairs[] (sorted by bucket) via exact per-(bucket,block) offsets.
__global__ __launch_bounds__(BLK) void p3_part_k(const int* __restrict__ rows, const int* __restrict__ cols,
                                                 const int* __restrict__ hist, int2* __restrict__ pairs,
                                                 int E, int nb) {
    __shared__ int tail[MAXNB];
    const int tid = threadIdx.x, g = blockIdx.x;
    for (int b = tid; b < nb; b += BLK) tail[b] = hist[b * GPART + g];
    __syncthreads();
    const int chunk = (E + GPART - 1) / GPART;
    const int start = g * chunk, end = min(E, start + chunk);
    for (int e = start + tid; e < end; e += BLK) {
        const int r = rows[e], c = cols[e];
        const int pos = atomicAdd(&tail[c >> NBSHIFT], 1);
        pairs[pos] = make_int2(r, c);
    }
}
// P4: one block per bucket. Degree hist -> local scan -> P (global starts), dinv, then srow fill.
__global__ __launch_bounds__(BLK) void p4_fill_k(const int2* __restrict__ pairs, const int* __restrict__ bstart,
                                                 int* __restrict__ P, float* __restrict__ dinv,
                                                 int* __restrict__ srow, int n) {
    __shared__ int dh[1 << NBSHIFT];
    __shared__ int tl[1 << NBSHIFT];
    const int b = blockIdx.x, t = threadIdx.x;
    const int base = b << NBSHIFT;
    const int nnod = min(1 << NBSHIFT, n - base);
    const int lo = bstart[b], hi = bstart[b + 1];
    dh[t] = 0; dh[256 + t] = 0;
    __syncthreads();
    for (int e = lo + t; e < hi; e += BLK) atomicAdd(&dh[pairs[e].y - base], 1);
    __syncthreads();
    const int v0 = dh[t], v1 = dh[256 + t];
    tl[t] = v0; tl[256 + t] = v1;
    __syncthreads();
    for (int o = 1; o < (1 << NBSHIFT); o <<= 1) {
        const int a0 = tl[t] + ((t >= o) ? tl[t - o] : 0);
        const int a1 = tl[256 + t] + ((256 + t >= o) ? tl[256 + t - o] : 0);
        __syncthreads();
        tl[t] = a0; tl[256 + t] = a1;
        __syncthreads();
    }
    const int s0 = lo + tl[t] - v0;          // exclusive start of node base+t
    const int s1 = lo + tl[256 + t] - v1;
    __syncthreads();
    tl[t] = s0; tl[256 + t] = s1;
    if (t < nnod)       { P[base + t] = s0;       dinv[base + t] = rsqrtf((float)v0 + 1.0f); }
    if (256 + t < nnod) { P[base + 256 + t] = s1; dinv[base + 256 + t] = rsqrtf((float)v1 + 1.0f); }
    __syncthreads();
    for (int e = lo + t; e < hi; e += BLK) {
        const int2 pr = pairs[e];
        const int pos = atomicAdd(&tl[pr.y - base], 1);
        srow[pos] = pr.x;
    }
}

// ================= aggregation by gather =================
// out[i] = g( dinv[i] * ( Tp[i] + sum_{e in in(i)} Tp[srow[e]] ) )
// PRE: g(v) = relu(v + b) * dinv[i]
template<int WD, bool PRE>
__global__ __launch_bounds__(BLK) void gather_k(const float* __restrict__ Tp, const int* __restrict__ P,
                                                const int* __restrict__ srow, const float* __restrict__ dinv,
                                                const float* __restrict__ bin, float* __restrict__ out,
                                                int n, int E) {
    const long gid = (long)blockIdx.x * BLK + threadIdx.x;
    const int i = (int)(gid / WD);
    const int f = (int)(gid % WD);
    if (i >= n) return;
    const int start = P[i];
    const int end = (i + 1 < n) ? P[i + 1] : E;
    float a0 = Tp[(long)i * WD + f];   // self-loop
    float a1 = 0.f, a2 = 0.f, a3 = 0.f, a4 = 0.f, a5 = 0.f, a6 = 0.f, a7 = 0.f;
    int e = start;
    const int ea = min(end, (start + 3) & ~3);   // align to int4
    for (; e < ea; e++) a0 += Tp[(long)srow[e] * WD + f];
    for (; e + 8 <= end; e += 8) {
        const int4 j0 = *(const int4*)&srow[e];
        const int4 j1 = *(const int4*)&srow[e + 4];
        a0 += Tp[(long)j0.x * WD + f]; a1 += Tp[(long)j0.y * WD + f];
        a2 += Tp[(long)j0.z * WD + f]; a3 += Tp[(long)j0.w * WD + f];
        a4 += Tp[(long)j1.x * WD + f]; a5 += Tp[(long)j1.y * WD + f];
        a6 += Tp[(long)j1.z * WD + f]; a7 += Tp[(long)j1.w * WD + f];
    }
    if (e + 4 <= end) {
        const int4 j0 = *(const int4*)&srow[e];
        a0 += Tp[(long)j0.x * WD + f]; a1 += Tp[(long)j0.y * WD + f];
        a2 += Tp[(long)j0.z * WD + f]; a3 += Tp[(long)j0.w * WD + f];
        e += 4;
    }
    for (; e < end; e++) a0 += Tp[(long)srow[e] * WD + f];
    const float d = dinv[i];
    float v = d * (((a0 + a1) + (a2 + a3)) + ((a4 + a5) + (a6 + a7)));
    if (PRE) v = fmaxf(v + bin[f], 0.f) * d;
    out[(long)i * WD + f] = v;
}

// ================= GEMM: out = f_out( f_in(H) @ W ) [ * dinv[row] ] =================
// RPT=8 for FO>=64: 32 FMA per k-step vs 9 LDS reads -> FMA-bound; halves W-stage traffic.
template<int FI, int FO, bool INB, bool OUTB, bool OUTRELU, bool OSC>
__global__ __launch_bounds__(BLK) void gemm_k(const float* __restrict__ H, const float* __restrict__ Wm,
                                              const float* __restrict__ bin, const float* __restrict__ bout,
                                              const float* __restrict__ dinv, float* __restrict__ out, int n) {
    constexpr int COLT = FO / 4;
    constexpr int RTH  = BLK / COLT;
    constexpr int RPT  = (FO >= 64) ? 8 : 4;
    constexpr int ROWS = RTH * RPT;
    constexpr int KC   = (FI > 64) ? 64 : FI;
    constexpr int NKB  = FI / KC;

    __shared__ float Wl[KC * FO];
    __shared__ float Hl[ROWS * (KC + 1)];

    const int tid    = threadIdx.x;
    const int colIdx = tid % COLT;
    const int rowIdx = tid / COLT;
    const long rowBase = (long)blockIdx.x * ROWS;

    float4 acc[RPT];
#pragma unroll
    for (int i = 0; i < RPT; i++) acc[i] = make_float4(0.f, 0.f, 0.f, 0.f);

    for (int kb = 0; kb < NKB; kb++) {
        if (kb) __syncthreads();
        for (int f = tid * 4; f < KC * FO; f += BLK * 4) {
            const int kr = f / FO, c = f % FO;
            *(float4*)&Wl[kr * FO + c] = ld4(&Wm[(kb * KC + kr) * FO + c]);
        }
        for (int f = tid * 4; f < ROWS * KC; f += BLK * 4) {
            const int rr = f / KC, kk = f % KC;
            const long r = rowBase + rr;
            float4 v = make_float4(0.f, 0.f, 0.f, 0.f);
            if (r < n) v = ld4(&H[r * FI + kb * KC + kk]);
            if (INB) {
                float4 b4 = ld4(&bin[kb * KC + kk]);
                v.x = fmaxf(v.x + b4.x, 0.f); v.y = fmaxf(v.y + b4.y, 0.f);
                v.z = fmaxf(v.z + b4.z, 0.f); v.w = fmaxf(v.w + b4.w, 0.f);
            }
            float* dst = &Hl[rr * (KC + 1) + kk];
            dst[0] = v.x; dst[1] = v.y; dst[2] = v.z; dst[3] = v.w;
        }
        __syncthreads();
#pragma unroll 8
        for (int k = 0; k < KC; k++) {
            const float4 w4 = *(const float4*)&Wl[k * FO + 4 * colIdx];
#pragma unroll
            for (int i = 0; i < RPT; i++) {
                const float hv = Hl[(rowIdx * RPT + i) * (KC + 1) + k];
                acc[i].x = fmaf(hv, w4.x, acc[i].x);
                acc[i].y = fmaf(hv, w4.y, acc[i].y);
                acc[i].z = fmaf(hv, w4.z, acc[i].z);
                acc[i].w = fmaf(hv, w4.w, acc[i].w);
            }
        }
    }

    float4 bo = make_float4(0.f, 0.f, 0.f, 0.f);
    if (OUTB) bo = ld4(&bout[4 * colIdx]);
#pragma unroll
    for (int i = 0; i < RPT; i++) {
        const long r = rowBase + rowIdx * RPT + i;
        if (r < n) {
            float4 v = acc[i];
            if (OUTB) { v.x += bo.x; v.y += bo.y; v.z += bo.z; v.w += bo.w; }
            if (OUTRELU) {
                v.x = fmaxf(v.x, 0.f); v.y = fmaxf(v.y, 0.f);
                v.z = fmaxf(v.z, 0.f); v.w = fmaxf(v.w, 0.f);
            }
            if (OSC) {
                const float d = dinv[r];
                v.x *= d; v.y *= d; v.z *= d; v.w *= d;
            }
            *(float4*)&out[r * FO + 4 * colIdx] = v;
        }
    }
}

extern "C" void kernel_launch(void* const* d_in, const int* in_sizes, int n_in,
                              void* d_out, int out_size, void* d_ws, size_t ws_size,
                              hipStream_t stream)
{
    const float* x  = (const float*)d_in[0];
    const int*   ei = (const int*)d_in[1];
    const float* W1 = (const float*)d_in[3];  const float* b1 = (const float*)d_in[4];
    const float* W2 = (const float*)d_in[5];  const float* b2 = (const float*)d_in[6];
    const float* W3 = (const float*)d_in[7];  const float* b3 = (const float*)d_in[8];
    const float* W4 = (const float*)d_in[9];  const float* b4 = (const float*)d_in[10];
    const float* W5 = (const float*)d_in[11]; const float* b5 = (const float*)d_in[12];
    const float* W6 = (const float*)d_in[13]; const float* b6 = (const float*)d_in[14];
    const float* Wf = (const float*)d_in[15]; const float* bf = (const float*)d_in[16];

    const int n = in_sizes[0] / 128;
    const int E = in_sizes[1] / 2;
    const int* rows = ei;       // source j
    const int* cols = ei + E;   // target i

    // workspace layout — total (n + E + n + 128n + 128n)*4 = 116,000,000 B,
    // strictly <= the 116,003,072 B footprint proven safe in R3/R5.
    // (R4's failure is attributed to +407KB ws overflow from a non-aliased hist.)
    int*   P    = (int*)d_ws;                        // n ints
    int*   srow = P + n;                             // E ints
    float* dinv = (float*)(srow + E);                // n floats
    float* bufA = dinv + n;                          // n*128 floats
    float* bufB = bufA + (size_t)n * 128;            // n*128 floats
    // pre-layer aliases (dead before first use of bufA/bufB by the layer pipeline):
    int2*  pairs = (int2*)bufA;                      // E int2 = 25.6MB <= 51.2MB
    int*   hist  = (int*)bufB;                       // MAXNB*GPART ints = 409KB
    int*   bstart= hist + MAXNB * GPART;             // nb+1 ints

    auto cdiv = [](long a, long b) { return (unsigned)((a + b - 1) / b); };
    const int nb = (n + (1 << NBSHIFT) - 1) >> NBSHIFT;

    // --- CSR build (atomic-free radix partition) ---
    p1_hist_k<<<GPART, BLK, 0, stream>>>(cols, hist, E, nb);
    p2a_k<<<1, 256, 0, stream>>>(hist, bstart, nb, E);
    p2b_k<<<nb, 256, 0, stream>>>(hist, bstart);
    p3_part_k<<<GPART, BLK, 0, stream>>>(rows, cols, hist, pairs, E, nb);
    p4_fill_k<<<nb, BLK, 0, stream>>>(pairs, bstart, P, dinv, srow, n);

    // --- layers ---
    // L1: t1' = (x@W1)*dinv ; a1 = gather(t1')          [deferred: +b1, relu]
    gemm_k<128, 64, false, false, false, true><<<cdiv(n, 128), BLK, 0, stream>>>(x, W1, nullptr, nullptr, dinv, bufA, n);
    gather_k<64, false><<<cdiv((long)n * 64, BLK), BLK, 0, stream>>>(bufA, P, srow, dinv, nullptr, bufB, n, E);

    // L2: t2' = (relu(a1+b1)@W2)*dinv ; a2 = gather     [deferred: +b2, relu]
    gemm_k<64, 32, true, false, false, true><<<cdiv(n, 128), BLK, 0, stream>>>(bufB, W2, b1, nullptr, dinv, bufA, n);
    gather_k<32, false><<<cdiv((long)n * 32, BLK), BLK, 0, stream>>>(bufA, P, srow, dinv, nullptr, bufB, n, E);

    // L3: t3' = (relu(a2+b2)@W3)*dinv ; gather w/ fused epilogue -> t4' = relu(a3+b3)*dinv
    gemm_k<32, 16, true, false, false, true><<<cdiv(n, 256), BLK, 0, stream>>>(bufB, W3, b2, nullptr, dinv, bufA, n);
    gather_k<16, true><<<cdiv((long)n * 16, BLK), BLK, 0, stream>>>(bufA, P, srow, dinv, b3, bufB, n, E);

    // L4: a4 = gather(t4') ; h4' = relu(a4@W4+b4)*dinv
    gather_k<16, false><<<cdiv((long)n * 16, BLK), BLK, 0, stream>>>(bufB, P, srow, dinv, nullptr, bufA, n, E);
    gemm_k<16, 32, false, true, true, true><<<cdiv(n, 128), BLK, 0, stream>>>(bufA, W4, nullptr, b4, dinv, bufB, n);

    // L5: a5 = gather(h4') ; h5' = relu(a5@W5+b5)*dinv
    gather_k<32, false><<<cdiv((long)n * 32, BLK), BLK, 0, stream>>>(bufB, P, srow, dinv, nullptr, bufA, n, E);
    gemm_k<32, 64, false, true, true, true><<<cdiv(n, 128), BLK, 0, stream>>>(bufA, W5, nullptr, b5, dinv, bufB, n);

    // L6: a6 = gather(h5') ; h6 = relu(a6@W6+b6)
    gather_k<64, false><<<cdiv((long)n * 64, BLK), BLK, 0, stream>>>(bufB, P, srow, dinv, nullptr, bufA, n, E);
    gemm_k<64, 128, false, true, true, false><<<cdiv(n, 64), BLK, 0, stream>>>(bufA, W6, nullptr, b6, nullptr, bufB, n);

    // final: out = h6 @ Wf + bf
    gemm_k<128, 128, false, true, false, false><<<cdiv(n, 64), BLK, 0, stream>>>(bufB, Wf, nullptr, bf, nullptr, (float*)d_out, n);
}

// Round 7
// 846.004 us; speedup vs baseline: 11.2184x; 1.0019x over previous
//
#include <hip/hip_runtime.h>

#define BLK 256
#define NBSHIFT 9     // 512 nodes per bucket
#define MAXNB 200     // supports n <= 102400
#define GPART 512     // partition blocks

__device__ __forceinline__ float4 ld4(const float* p) { return *(const float4*)p; }
__device__ __forceinline__ void add4(float4& a, const float4 b) {
    a.x += b.x; a.y += b.y; a.z += b.z; a.w += b.w;
}

// ================= CSR build: atomic-free radix partition by col>>NBSHIFT =================
// P1: per-block histogram over buckets. hist[b*GPART + g] = count of bucket b in block g's chunk.
__global__ __launch_bounds__(BLK) void p1_hist_k(const int* __restrict__ cols, int* __restrict__ hist,
                                                 int E, int nb) {
    __shared__ int h[MAXNB];
    const int tid = threadIdx.x, g = blockIdx.x;
    for (int b = tid; b < nb; b += BLK) h[b] = 0;
    __syncthreads();
    const int chunk = (E + GPART - 1) / GPART;
    const int start = g * chunk, end = min(E, start + chunk);
    for (int e = start + tid; e < end; e += BLK) atomicAdd(&h[cols[e] >> NBSHIFT], 1);
    __syncthreads();
    for (int b = tid; b < nb; b += BLK) hist[b * GPART + g] = h[b];
}
// P2a: bucket totals + exclusive scan -> bstart[0..nb], bstart[nb]=E. Single block.
__global__ __launch_bounds__(256) void p2a_k(const int* __restrict__ hist, int* __restrict__ bstart,
                                             int nb, int E) {
    __shared__ int s[256];
    const int t = threadIdx.x;
    int tot = 0;
    if (t < nb) {
        const int* hp = &hist[t * GPART];
        for (int g = 0; g < GPART; g++) tot += hp[g];
    }
    s[t] = tot;
    __syncthreads();
    for (int o = 1; o < 256; o <<= 1) {
        int v = s[t] + ((t >= o) ? s[t - o] : 0);
        __syncthreads();
        s[t] = v;
        __syncthreads();
    }
    if (t < nb) bstart[t] = s[t] - tot;
    if (t == 0) bstart[nb] = E;
}
// P2b: per-bucket exclusive scan over its GPART block-counts, +bstart -> absolute offsets (in place).
__global__ __launch_bounds__(256) void p2b_k(int* __restrict__ hist, const int* __restrict__ bstart) {
    __shared__ int s[GPART];
    const int b = blockIdx.x, t = threadIdx.x;
    const int v0 = hist[b * GPART + t], v1 = hist[b * GPART + 256 + t];
    s[t] = v0; s[256 + t] = v1;
    __syncthreads();
    for (int o = 1; o < GPART; o <<= 1) {
        const int a0 = s[t] + ((t >= o) ? s[t - o] : 0);
        const int a1 = s[256 + t] + ((256 + t >= o) ? s[256 + t - o] : 0);
        __syncthreads();
        s[t] = a0; s[256 + t] = a1;
        __syncthreads();
    }
    const int base = bstart[b];
    hist[b * GPART + t] = base + s[t] - v0;
    hist[b * GPART + 256 + t] = base + s[256 + t] - v1;
}
// P3: partition edges into pairs[] (sorted by bucket) via exact per-(bucket,block) offsets.
__global__ __launch_bounds__(BLK) void p3_part_k(const int* __restrict__ rows, const int* __restrict__ cols,
                                                 const int* __restrict__ hist, int2* __restrict__ pairs,
                                                 int E, int nb) {
    __shared__ int tail[MAXNB];
    const int tid = threadIdx.x, g = blockIdx.x;
    for (int b = tid; b < nb; b += BLK) tail[b] = hist[b * GPART + g];
    __syncthreads();
    const int chunk = (E + GPART - 1) / GPART;
    const int start = g * chunk, end = min(E, start + chunk);
    for (int e = start + tid; e < end; e += BLK) {
        const int r = rows[e], c = cols[e];
        const int pos = atomicAdd(&tail[c >> NBSHIFT], 1);
        pairs[pos] = make_int2(r, c);
    }
}
// P4: one block per bucket. Degree hist -> local scan -> P (global starts), dinv, then srow fill.
__global__ __launch_bounds__(BLK) void p4_fill_k(const int2* __restrict__ pairs, const int* __restrict__ bstart,
                                                 int* __restrict__ P, float* __restrict__ dinv,
                                                 int* __restrict__ srow, int n) {
    __shared__ int dh[1 << NBSHIFT];
    __shared__ int tl[1 << NBSHIFT];
    const int b = blockIdx.x, t = threadIdx.x;
    const int base = b << NBSHIFT;
    const int nnod = min(1 << NBSHIFT, n - base);
    const int lo = bstart[b], hi = bstart[b + 1];
    dh[t] = 0; dh[256 + t] = 0;
    __syncthreads();
    for (int e = lo + t; e < hi; e += BLK) atomicAdd(&dh[pairs[e].y - base], 1);
    __syncthreads();
    const int v0 = dh[t], v1 = dh[256 + t];
    tl[t] = v0; tl[256 + t] = v1;
    __syncthreads();
    for (int o = 1; o < (1 << NBSHIFT); o <<= 1) {
        const int a0 = tl[t] + ((t >= o) ? tl[t - o] : 0);
        const int a1 = tl[256 + t] + ((256 + t >= o) ? tl[256 + t - o] : 0);
        __syncthreads();
        tl[t] = a0; tl[256 + t] = a1;
        __syncthreads();
    }
    const int s0 = lo + tl[t] - v0;          // exclusive start of node base+t
    const int s1 = lo + tl[256 + t] - v1;
    __syncthreads();
    tl[t] = s0; tl[256 + t] = s1;
    if (t < nnod)       { P[base + t] = s0;       dinv[base + t] = rsqrtf((float)v0 + 1.0f); }
    if (256 + t < nnod) { P[base + 256 + t] = s1; dinv[base + 256 + t] = rsqrtf((float)v1 + 1.0f); }
    __syncthreads();
    for (int e = lo + t; e < hi; e += BLK) {
        const int2 pr = pairs[e];
        const int pos = atomicAdd(&tl[pr.y - base], 1);
        srow[pos] = pr.x;
    }
}

// ================= aggregation by gather (float4 per lane) =================
// out[i] = g( dinv[i] * ( Tp[i] + sum_{e in in(i)} Tp[srow[e]] ) )
// PRE: g(v) = relu(v + b) * dinv[i]
// Each thread owns 4 features of one node: WD/4 lanes per node, dwordx4 row loads.
template<int WD, bool PRE>
__global__ __launch_bounds__(BLK) void gather4_k(const float* __restrict__ Tp, const int* __restrict__ P,
                                                 const int* __restrict__ srow, const float* __restrict__ dinv,
                                                 const float* __restrict__ bin, float* __restrict__ out,
                                                 int n, int E) {
    constexpr int LPN = WD / 4;   // lanes per node
    const long gid = (long)blockIdx.x * BLK + threadIdx.x;
    const int i = (int)(gid / LPN);
    if (i >= n) return;
    const int q = (int)(gid % LPN) * 4;
    const int start = P[i];
    const int end = (i + 1 < n) ? P[i + 1] : E;
    const float d = dinv[i];
    const float* __restrict__ Tq = Tp + q;
    float4 A0 = ld4(&Tq[(long)i * WD]);   // self-loop
    float4 A1 = make_float4(0.f, 0.f, 0.f, 0.f), A2 = A1, A3 = A1, A4 = A1, A5 = A1, A6 = A1, A7 = A1;
    int e = start;
    const int ea = min(end, (start + 3) & ~3);   // align srow to int4
    for (; e < ea; e++) add4(A0, ld4(&Tq[(long)srow[e] * WD]));
    for (; e + 8 <= end; e += 8) {
        const int4 j0 = *(const int4*)&srow[e];
        const int4 j1 = *(const int4*)&srow[e + 4];
        add4(A0, ld4(&Tq[(long)j0.x * WD])); add4(A1, ld4(&Tq[(long)j0.y * WD]));
        add4(A2, ld4(&Tq[(long)j0.z * WD])); add4(A3, ld4(&Tq[(long)j0.w * WD]));
        add4(A4, ld4(&Tq[(long)j1.x * WD])); add4(A5, ld4(&Tq[(long)j1.y * WD]));
        add4(A6, ld4(&Tq[(long)j1.z * WD])); add4(A7, ld4(&Tq[(long)j1.w * WD]));
    }
    if (e + 4 <= end) {
        const int4 j0 = *(const int4*)&srow[e];
        add4(A0, ld4(&Tq[(long)j0.x * WD])); add4(A1, ld4(&Tq[(long)j0.y * WD]));
        add4(A2, ld4(&Tq[(long)j0.z * WD])); add4(A3, ld4(&Tq[(long)j0.w * WD]));
        e += 4;
    }
    for (; e < end; e++) add4(A0, ld4(&Tq[(long)srow[e] * WD]));
    add4(A0, A1); add4(A2, A3); add4(A4, A5); add4(A6, A7);
    add4(A0, A2); add4(A4, A6); add4(A0, A4);
    float4 v; v.x = d * A0.x; v.y = d * A0.y; v.z = d * A0.z; v.w = d * A0.w;
    if (PRE) {
        const float4 b4 = ld4(&bin[q]);
        v.x = fmaxf(v.x + b4.x, 0.f) * d; v.y = fmaxf(v.y + b4.y, 0.f) * d;
        v.z = fmaxf(v.z + b4.z, 0.f) * d; v.w = fmaxf(v.w + b4.w, 0.f) * d;
    }
    *(float4*)&out[(long)i * WD + q] = v;
}

// ================= GEMM: out = f_out( f_in(H) @ W ) [ * dinv[row] ] =================
// RPT=8 for FO>=64: 32 FMA per k-step vs 9 LDS reads -> FMA-bound; halves W-stage traffic.
template<int FI, int FO, bool INB, bool OUTB, bool OUTRELU, bool OSC>
__global__ __launch_bounds__(BLK) void gemm_k(const float* __restrict__ H, const float* __restrict__ Wm,
                                              const float* __restrict__ bin, const float* __restrict__ bout,
                                              const float* __restrict__ dinv, float* __restrict__ out, int n) {
    constexpr int COLT = FO / 4;
    constexpr int RTH  = BLK / COLT;
    constexpr int RPT  = (FO >= 64) ? 8 : 4;
    constexpr int ROWS = RTH * RPT;
    constexpr int KC   = (FI > 64) ? 64 : FI;
    constexpr int NKB  = FI / KC;

    __shared__ float Wl[KC * FO];
    __shared__ float Hl[ROWS * (KC + 1)];

    const int tid    = threadIdx.x;
    const int colIdx = tid % COLT;
    const int rowIdx = tid / COLT;
    const long rowBase = (long)blockIdx.x * ROWS;

    float4 acc[RPT];
#pragma unroll
    for (int i = 0; i < RPT; i++) acc[i] = make_float4(0.f, 0.f, 0.f, 0.f);

    for (int kb = 0; kb < NKB; kb++) {
        if (kb) __syncthreads();
        for (int f = tid * 4; f < KC * FO; f += BLK * 4) {
            const int kr = f / FO, c = f % FO;
            *(float4*)&Wl[kr * FO + c] = ld4(&Wm[(kb * KC + kr) * FO + c]);
        }
        for (int f = tid * 4; f < ROWS * KC; f += BLK * 4) {
            const int rr = f / KC, kk = f % KC;
            const long r = rowBase + rr;
            float4 v = make_float4(0.f, 0.f, 0.f, 0.f);
            if (r < n) v = ld4(&H[r * FI + kb * KC + kk]);
            if (INB) {
                float4 b4 = ld4(&bin[kb * KC + kk]);
                v.x = fmaxf(v.x + b4.x, 0.f); v.y = fmaxf(v.y + b4.y, 0.f);
                v.z = fmaxf(v.z + b4.z, 0.f); v.w = fmaxf(v.w + b4.w, 0.f);
            }
            float* dst = &Hl[rr * (KC + 1) + kk];
            dst[0] = v.x; dst[1] = v.y; dst[2] = v.z; dst[3] = v.w;
        }
        __syncthreads();
#pragma unroll 8
        for (int k = 0; k < KC; k++) {
            const float4 w4 = *(const float4*)&Wl[k * FO + 4 * colIdx];
#pragma unroll
            for (int i = 0; i < RPT; i++) {
                const float hv = Hl[(rowIdx * RPT + i) * (KC + 1) + k];
                acc[i].x = fmaf(hv, w4.x, acc[i].x);
                acc[i].y = fmaf(hv, w4.y, acc[i].y);
                acc[i].z = fmaf(hv, w4.z, acc[i].z);
                acc[i].w = fmaf(hv, w4.w, acc[i].w);
            }
        }
    }

    float4 bo = make_float4(0.f, 0.f, 0.f, 0.f);
    if (OUTB) bo = ld4(&bout[4 * colIdx]);
#pragma unroll
    for (int i = 0; i < RPT; i++) {
        const long r = rowBase + rowIdx * RPT + i;
        if (r < n) {
            float4 v = acc[i];
            if (OUTB) { v.x += bo.x; v.y += bo.y; v.z += bo.z; v.w += bo.w; }
            if (OUTRELU) {
                v.x = fmaxf(v.x, 0.f); v.y = fmaxf(v.y, 0.f);
                v.z = fmaxf(v.z, 0.f); v.w = fmaxf(v.w, 0.f);
            }
            if (OSC) {
                const float d = dinv[r];
                v.x *= d; v.y *= d; v.z *= d; v.w *= d;
            }
            *(float4*)&out[r * FO + 4 * colIdx] = v;
        }
    }
}

extern "C" void kernel_launch(void* const* d_in, const int* in_sizes, int n_in,
                              void* d_out, int out_size, void* d_ws, size_t ws_size,
                              hipStream_t stream)
{
    const float* x  = (const float*)d_in[0];
    const int*   ei = (const int*)d_in[1];
    const float* W1 = (const float*)d_in[3];  const float* b1 = (const float*)d_in[4];
    const float* W2 = (const float*)d_in[5];  const float* b2 = (const float*)d_in[6];
    const float* W3 = (const float*)d_in[7];  const float* b3 = (const float*)d_in[8];
    const float* W4 = (const float*)d_in[9];  const float* b4 = (const float*)d_in[10];
    const float* W5 = (const float*)d_in[11]; const float* b5 = (const float*)d_in[12];
    const float* W6 = (const float*)d_in[13]; const float* b6 = (const float*)d_in[14];
    const float* Wf = (const float*)d_in[15]; const float* bf = (const float*)d_in[16];

    const int n = in_sizes[0] / 128;
    const int E = in_sizes[1] / 2;
    const int* rows = ei;       // source j
    const int* cols = ei + E;   // target i

    // workspace layout — total (n + E + n + 128n + 128n)*4 = 116,000,000 B (proven safe in R6).
    int*   P    = (int*)d_ws;                        // n ints
    int*   srow = P + n;                             // E ints (16B-aligned for n%4==0)
    float* dinv = (float*)(srow + E);                // n floats
    float* bufA = dinv + n;                          // n*128 floats
    float* bufB = bufA + (size_t)n * 128;            // n*128 floats
    // pre-layer aliases (dead before first use of bufA/bufB by the layer pipeline):
    int2*  pairs = (int2*)bufA;                      // E int2 = 25.6MB <= 51.2MB
    int*   hist  = (int*)bufB;                       // MAXNB*GPART ints = 409KB
    int*   bstart= hist + MAXNB * GPART;             // nb+1 ints

    auto cdiv = [](long a, long b) { return (unsigned)((a + b - 1) / b); };
    const int nb = (n + (1 << NBSHIFT) - 1) >> NBSHIFT;

    // --- CSR build (atomic-free radix partition) ---
    p1_hist_k<<<GPART, BLK, 0, stream>>>(cols, hist, E, nb);
    p2a_k<<<1, 256, 0, stream>>>(hist, bstart, nb, E);
    p2b_k<<<nb, 256, 0, stream>>>(hist, bstart);
    p3_part_k<<<GPART, BLK, 0, stream>>>(rows, cols, hist, pairs, E, nb);
    p4_fill_k<<<nb, BLK, 0, stream>>>(pairs, bstart, P, dinv, srow, n);

    // --- layers ---
    // L1: t1' = (x@W1)*dinv ; a1 = gather(t1')          [deferred: +b1, relu]
    gemm_k<128, 64, false, false, false, true><<<cdiv(n, 128), BLK, 0, stream>>>(x, W1, nullptr, nullptr, dinv, bufA, n);
    gather4_k<64, false><<<cdiv((long)n * 16, BLK), BLK, 0, stream>>>(bufA, P, srow, dinv, nullptr, bufB, n, E);

    // L2: t2' = (relu(a1+b1)@W2)*dinv ; a2 = gather     [deferred: +b2, relu]
    gemm_k<64, 32, true, false, false, true><<<cdiv(n, 128), BLK, 0, stream>>>(bufB, W2, b1, nullptr, dinv, bufA, n);
    gather4_k<32, false><<<cdiv((long)n * 8, BLK), BLK, 0, stream>>>(bufA, P, srow, dinv, nullptr, bufB, n, E);

    // L3: t3' = (relu(a2+b2)@W3)*dinv ; gather w/ fused epilogue -> t4' = relu(a3+b3)*dinv
    gemm_k<32, 16, true, false, false, true><<<cdiv(n, 256), BLK, 0, stream>>>(bufB, W3, b2, nullptr, dinv, bufA, n);
    gather4_k<16, true><<<cdiv((long)n * 4, BLK), BLK, 0, stream>>>(bufA, P, srow, dinv, b3, bufB, n, E);

    // L4: a4 = gather(t4') ; h4' = relu(a4@W4+b4)*dinv
    gather4_k<16, false><<<cdiv((long)n * 4, BLK), BLK, 0, stream>>>(bufB, P, srow, dinv, nullptr, bufA, n, E);
    gemm_k<16, 32, false, true, true, true><<<cdiv(n, 128), BLK, 0, stream>>>(bufA, W4, nullptr, b4, dinv, bufB, n);

    // L5: a5 = gather(h4') ; h5' = relu(a5@W5+b5)*dinv
    gather4_k<32, false><<<cdiv((long)n * 8, BLK), BLK, 0, stream>>>(bufB, P, srow, dinv, nullptr, bufA, n, E);
    gemm_k<32, 64, false, true, true, true><<<cdiv(n, 128), BLK, 0, stream>>>(bufA, W5, nullptr, b5, dinv, bufB, n);

    // L6: a6 = gather(h5') ; h6 = relu(a6@W6+b6)
    gather4_k<64, false><<<cdiv((long)n * 16, BLK), BLK, 0, stream>>>(bufB, P, srow, dinv, nullptr, bufA, n, E);
    gemm_k<64, 128, false, true, true, false><<<cdiv(n, 64), BLK, 0, stream>>>(bufA, W6, nullptr, b6, nullptr, bufB, n);

    // final: out = h6 @ Wf + bf
    gemm_k<128, 128, false, true, false, false><<<cdiv(n, 64), BLK, 0, stream>>>(bufB, Wf, nullptr, bf, nullptr, (float*)d_out, n);
}